// Round 10
// baseline (1394.151 us; speedup 1.0000x reference)
//
#include <hip/hip_runtime.h>
#include <stdint.h>

// ---------------------------------------------------------------------------
// Decoder: GRU(seq) + attention + dense + vocab projection
// H=512, V=32000, B=16, Td=Te=64
// Round 14 (base = R13 best, 655.6us = GRU 279 + non-GRU 376):
//  - GRU exchange protocol FROZEN (R6 topology, floor 4.3-4.4us/step,
//    reproduced 6x). This round shortens only the intra-block compute:
//    lane (g,q) = (lane>>4, lane&15) holds 3 gate-rows of unit j0+g over
//    k-slice [q*32,q*32+32) -> butterfly is 12 shfl over offsets {1,2,4,8}
//    (DPP-friendly, no cross-32 ds_permute) vs old 72 shfl / 6 stages.
//    h staged LINEAR in LDS (wave0 polls units lane+64i, same coalescing,
//    conflict-free store); readers rotate chunks ((c+q)&7) -> 2-way
//    conflicts (free). Publish/poll/barrier structure untouched.
//  - gemm_logits: 256x256 tiles (8 waves = 2x4 of 128x64, acc[8][4]):
//    staged traffic 384->256MB, 500 blocks, 2x arithmetic intensity.
//  - W_out f32->bf16 in the big preproc (R10 placement; R11/R12 both lost).
//  - Pair-operand GEMMs from precomputed hi/lo splits; attn vectorized.
//  - split-bf16 MFMA everywhere (AhBh+AhBl+AlBh, ~1.6e-5 rel err).
// ---------------------------------------------------------------------------

#define Hdim 512
#define Vdim 32000
#define Bdim 16
#define Tdim 64
#define BT   1024   // B*Td rows
#define GANG_BLOCKS 16

typedef __attribute__((ext_vector_type(8))) short bf16x8;
typedef __attribute__((ext_vector_type(4))) float f32x4;

static __device__ __forceinline__ unsigned short f2bf(float f) {
    unsigned u = __float_as_uint(f);
    u = u + 0x7FFFu + ((u >> 16) & 1u);   // RNE
    return (unsigned short)(u >> 16);
}
static __device__ __forceinline__ float bf2f(unsigned short h) {
    return __uint_as_float((unsigned)h << 16);
}
static __device__ __forceinline__ float fast_tanh(float x) {
    return 2.f / (1.f + __expf(-2.f * x)) - 1.f;
}

// --------------------------- merged preprocessing --------------------------
// Zero hslots+zbias, five f32->(hi,lo) splits, W_out f32->bf16.

#define U_ZERO 8320      // (16384 u64 -> 32768 f) + 512 f zbias, /4
#define U_INP  131072    // 1024*512/4
#define U_WIH  196608    // 1536*512/4
#define U_WAT  131072    // 512*1024/4
#define U_WDE  131072    // 512*1024/4
#define U_ENC  131072    // 1024*512/4
#define U_SPLIT (U_INP + U_WIH + U_WAT + U_WDE + U_ENC)
#define U_WOUT 4096000   // 32000*512/4
#define U_TOT  (U_ZERO + U_SPLIT + U_WOUT)

__global__ __launch_bounds__(256) void preproc_kernel(
    const float* __restrict__ input_seqs,
    const float* __restrict__ W_ih,
    const float* __restrict__ W_attn,
    const float* __restrict__ W_dense,
    const float* __restrict__ enc,
    const float* __restrict__ W_out,
    float* __restrict__ zero_base,      // hslots..zbias, 33280 floats
    unsigned short* __restrict__ inp_h, unsigned short* __restrict__ inp_l,
    unsigned short* __restrict__ Wih_h, unsigned short* __restrict__ Wih_l,
    unsigned short* __restrict__ Wat_h, unsigned short* __restrict__ Wat_l,
    unsigned short* __restrict__ Wde_h, unsigned short* __restrict__ Wde_l,
    unsigned short* __restrict__ enc_h, unsigned short* __restrict__ enc_l,
    unsigned short* __restrict__ Wout_bf)
{
    int u = blockIdx.x * 256 + threadIdx.x;
    const int stride = gridDim.x * 256;
    for (; u < U_TOT; u += stride) {
        int r = u;
        if (r < U_ZERO) {
            float4 z; z.x = 0.f; z.y = 0.f; z.z = 0.f; z.w = 0.f;
            *(float4*)(zero_base + r * 4) = z;
            continue;
        }
        r -= U_ZERO;
        if (r >= U_SPLIT) {
            int i = (r - U_SPLIT) * 4;
            float4 v = *(const float4*)(W_out + i);
            unsigned short h[4] = {f2bf(v.x), f2bf(v.y), f2bf(v.z), f2bf(v.w)};
            *(uint2*)(Wout_bf + i) = *(const uint2*)h;
            continue;
        }
        const float* src; unsigned short* hi; unsigned short* lo;
        if (r < U_INP) { src = input_seqs; hi = inp_h; lo = inp_l; }
        else { r -= U_INP;
            if (r < U_WIH) { src = W_ih; hi = Wih_h; lo = Wih_l; }
            else { r -= U_WIH;
                if (r < U_WAT) { src = W_attn; hi = Wat_h; lo = Wat_l; }
                else { r -= U_WAT;
                    if (r < U_WDE) { src = W_dense; hi = Wde_h; lo = Wde_l; }
                    else { r -= U_WDE; src = enc; hi = enc_h; lo = enc_l; }
                }
            }
        }
        int i = r * 4;
        float4 v = *(const float4*)(src + i);
        float f[4] = {v.x, v.y, v.z, v.w};
        unsigned short h[4], l[4];
#pragma unroll
        for (int k = 0; k < 4; ++k) {
            h[k] = f2bf(f[k]);
            l[k] = f2bf(f[k] - bf2f(h[k]));
        }
        *(uint2*)(hi + i) = *(const uint2*)h;
        *(uint2*)(lo + i) = *(const uint2*)l;
    }
}

// ----------------------- split-bf16 MFMA GEMM body -------------------------

struct GemmSmem {
    unsigned short AsH[128 * 40];
    unsigned short AsL[128 * 40];
    unsigned short BsH[128 * 40];
    unsigned short BsL[128 * 40];
};

static __device__ __forceinline__ void gemm_tile(
    GemmSmem& S, int m0, int n0,
    const unsigned short* __restrict__ Ah, const unsigned short* __restrict__ Al, int lda,
    const unsigned short* __restrict__ Bh, const unsigned short* __restrict__ Bl, int ldb,
    const float* __restrict__ bias,
    float* __restrict__ C, unsigned short* __restrict__ Cb, int ldc,
    int K, int act)
{
    const int tid = threadIdx.x;
    const int wave = tid >> 6, lane = tid & 63;
    const int wm = (wave >> 1) * 64, wn = (wave & 1) * 64;
    const int lrow = lane & 15, lk = (lane >> 4) * 8;

    f32x4 acc[4][4];
#pragma unroll
    for (int i = 0; i < 4; ++i)
#pragma unroll
        for (int j = 0; j < 4; ++j) acc[i][j] = (f32x4){0.f, 0.f, 0.f, 0.f};

    for (int k0 = 0; k0 < K; k0 += 32) {
#pragma unroll
        for (int i = 0; i < 2; ++i) {
            int idx = tid + i * 256;        // 0..511
            int rr = idx >> 2, kq = (idx & 3) * 8;
            size_t ao = (size_t)(m0 + rr) * lda + k0 + kq;
            size_t bo = (size_t)(n0 + rr) * ldb + k0 + kq;
            *(uint4*)(&S.AsH[rr * 40 + kq]) = *(const uint4*)(Ah + ao);
            *(uint4*)(&S.AsL[rr * 40 + kq]) = *(const uint4*)(Al + ao);
            *(uint4*)(&S.BsH[rr * 40 + kq]) = *(const uint4*)(Bh + bo);
            *(uint4*)(&S.BsL[rr * 40 + kq]) = *(const uint4*)(Bl + bo);
        }
        __syncthreads();
        bf16x8 ah[4], al[4], bh[4], bl[4];
#pragma unroll
        for (int i = 0; i < 4; ++i) {
            ah[i] = *(const bf16x8*)(&S.AsH[(wm + i * 16 + lrow) * 40 + lk]);
            al[i] = *(const bf16x8*)(&S.AsL[(wm + i * 16 + lrow) * 40 + lk]);
        }
#pragma unroll
        for (int j = 0; j < 4; ++j) {
            bh[j] = *(const bf16x8*)(&S.BsH[(wn + j * 16 + lrow) * 40 + lk]);
            bl[j] = *(const bf16x8*)(&S.BsL[(wn + j * 16 + lrow) * 40 + lk]);
        }
#pragma unroll
        for (int i = 0; i < 4; ++i)
#pragma unroll
            for (int j = 0; j < 4; ++j) {
                acc[i][j] = __builtin_amdgcn_mfma_f32_16x16x32_bf16(ah[i], bh[j], acc[i][j], 0, 0, 0);
                acc[i][j] = __builtin_amdgcn_mfma_f32_16x16x32_bf16(ah[i], bl[j], acc[i][j], 0, 0, 0);
                acc[i][j] = __builtin_amdgcn_mfma_f32_16x16x32_bf16(al[i], bh[j], acc[i][j], 0, 0, 0);
            }
        __syncthreads();
    }

    const int crow = m0 + wm + ((lane >> 4) * 4);
    const int ccol = n0 + wn + (lane & 15);
#pragma unroll
    for (int i = 0; i < 4; ++i) {
#pragma unroll
        for (int j = 0; j < 4; ++j) {
            int col = ccol + j * 16;
            float bv = bias[col];
#pragma unroll
            for (int rr = 0; rr < 4; ++rr) {
                int row = crow + i * 16 + rr;
                float v = acc[i][j][rr] + bv;
                if (act == 1) v = fast_tanh(v);
                if (Cb) Cb[(size_t)row * ldc + col] = f2bf(v);
                else    C [(size_t)row * ldc + col] = v;
            }
        }
    }
}

// single-job GEMM (dec_p, dense)
__global__ __launch_bounds__(256) void gemm_split(
    const unsigned short* __restrict__ Ah, const unsigned short* __restrict__ Al, int lda,
    const unsigned short* __restrict__ Bh, const unsigned short* __restrict__ Bl, int ldb,
    const float* __restrict__ bias,
    float* __restrict__ C, unsigned short* __restrict__ Cb, int ldc,
    int K, int act)
{
    __shared__ GemmSmem S;
    gemm_tile(S, blockIdx.y * 128, blockIdx.x * 128,
              Ah, Al, lda, Bh, Bl, ldb, bias, C, Cb, ldc, K, act);
}

// dual-job GEMM: job A = x_proj (96 blocks), job B = enc_p (32 blocks)
__global__ __launch_bounds__(256) void gemm_split_dual(
    const unsigned short* __restrict__ A0h, const unsigned short* __restrict__ A0l,
    const unsigned short* __restrict__ B0h, const unsigned short* __restrict__ B0l,
    const float* __restrict__ bias0, float* __restrict__ C0,
    const unsigned short* __restrict__ A1h, const unsigned short* __restrict__ A1l,
    const unsigned short* __restrict__ B1h, const unsigned short* __restrict__ B1l,
    const float* __restrict__ bias1, float* __restrict__ C1)
{
    __shared__ GemmSmem S;
    const int bid = blockIdx.x;
    if (bid < 96) {
        gemm_tile(S, (bid / 12) * 128, (bid % 12) * 128,
                  A0h, A0l, Hdim, B0h, B0l, Hdim, bias0, C0, nullptr, 1536, Hdim, 0);
    } else {
        int r = bid - 96;
        gemm_tile(S, (r / 4) * 128, (r % 4) * 128,
                  A1h, A1l, Hdim, B1h, B1l, 1024, bias1, C1, nullptr, Hdim, Hdim, 0);
    }
}

// --------------------------- persistent GRU --------------------------------
// Exchange protocol: R6 topology, FROZEN (floor 4.3-4.4us/step, 6x repro).
// 16 gangs x 16 blocks x 512 thr; h unit j parity p at
// hslots[p*8192 + b*512 + j] as (tag=t)<<32|bits; wave0 polls, one
// __syncthreads, all 8 waves compute; publish = plain relaxed agent store;
// y buffered in LDS, coalesced writeback after the loop.
// R14 compute shortening (protocol untouched):
//  - lane (g,q) = (lane>>4, lane&15); lane owns unit j = j0+g's THREE
//    gate-rows over k-slice [q*32, q*32+32) (w4[3][8] float4 regs).
//  - wave0 polls units {lane + 64*i} (same coalescing: per i, 64 lanes
//    read 64 consecutive u64s) and stores hl LINEAR (conflict-free).
//  - readers: float4 chunk rotation ((c+q)&7) -> 2-way conflicts (free).
//  - butterfly: 12 shfl over offsets {1,2,4,8} within 16-lane groups
//    (DPP-friendly) vs old 72 shfl incl. cross-32 permutes.
//  - publishers = lanes with q==0 (one per group), unit j0+g.

__global__ __launch_bounds__(512) void gru_persistent(
    const float* __restrict__ xp,        // (1024,1536) rows = b*64+t
    const float* __restrict__ Whh,       // (1536,512)
    const float* __restrict__ bhh,       // (1536)
    const int*   __restrict__ lengths,   // (16)
    unsigned long long* __restrict__ hslots, // (2,16,512) tagged; zero-init
    unsigned short* __restrict__ cath,   // (1024,1024) cols [0,512)
    unsigned short* __restrict__ catl,
    float* __restrict__ h_last)          // (16,512)
{
    const int bid  = blockIdx.x;
    const int b    = bid >> 4;           // gang = batch
    const int blk  = bid & 15;
    const int tid  = threadIdx.x;
    const int wave = tid >> 6, lane = tid & 63;
    const int g    = lane >> 4;          // group 0..3 -> unit j0+g
    const int q    = lane & 15;          // k-slice index
    const int j0   = blk * 32 + wave * 4;
    const int j    = j0 + g;             // this lane's unit

    __shared__ float hl[2][512];                // LINEAR h[u]
    __shared__ unsigned short yh_buf[64][32];   // [t][unit-in-block] hi
    __shared__ unsigned short yl_buf[64][32];   // [t][unit-in-block] lo

    // --- W_hh: 3 gate-rows of unit j, k-slice q*32..+32 (float4 x 8) ---
    float4 w4[3][8];
#pragma unroll
    for (int gg = 0; gg < 3; ++gg) {
        const float4* src = (const float4*)(Whh + (size_t)(gg * 512 + j) * Hdim + q * 32);
#pragma unroll
        for (int c = 0; c < 8; ++c) w4[gg][c] = src[c];
    }

    float bh_r = 0.f, bh_z = 0.f, bh_n = 0.f;
    if (q == 0) {
        bh_r = bhh[j]; bh_z = bhh[512 + j]; bh_n = bhh[1024 + j];
    }
    const int len_b = lengths[b];
    float hprev = 0.f;                   // publisher lane's own h[b][j]

    const size_t PSTR = (size_t)Bdim * Hdim;           // parity stride
    unsigned long long* gslot = hslots + (size_t)b * Hdim;
    const float* xbase = xp + (size_t)b * Tdim * 1536;

    for (int t = 0; t < Tdim; ++t) {
        const int par = t & 1;

        // xp loads are independent of h -> issue early
        float xr = 0.f, xz = 0.f, xn = 0.f;
        if (q == 0) {
            const float* xrow = xbase + (size_t)t * 1536;
            xr = xrow[j]; xz = xrow[512 + j]; xn = xrow[1024 + j];
        }

        // wave 0: poll units {lane + 64*i} (tag==t), store LINEAR
        if (wave == 0) {
            const unsigned long long* sl = gslot + (size_t)par * PSTR;
            unsigned long long v[8];
            bool ok;
            do {
#pragma unroll
                for (int i = 0; i < 8; ++i)
                    v[i] = __hip_atomic_load(sl + lane + 64 * i, __ATOMIC_RELAXED,
                                             __HIP_MEMORY_SCOPE_AGENT);
                ok = true;
#pragma unroll
                for (int i = 0; i < 8; ++i)
                    ok = ok && ((unsigned)(v[i] >> 32) == (unsigned)t);
            } while (!ok);
#pragma unroll
            for (int i = 0; i < 8; ++i)
                hl[par][lane + 64 * i] = __uint_as_float((unsigned)v[i]);
        }
        __syncthreads();                  // SYNC_t: hl[par] ready

        // partial dots: 3 gates x 32 k-elems, rotated chunks (2-way free)
        float p0 = 0.f, p1 = 0.f, p2 = 0.f;
        const float4* h4 = (const float4*)(&hl[par][q * 32]);
#pragma unroll
        for (int c = 0; c < 8; ++c) {
            int ch = (c + q) & 7;
            float4 hv = h4[ch];
            float4 a0 = w4[0][ch], a1 = w4[1][ch], a2 = w4[2][ch];
            p0 += a0.x * hv.x + a0.y * hv.y + a0.z * hv.z + a0.w * hv.w;
            p1 += a1.x * hv.x + a1.y * hv.y + a1.z * hv.z + a1.w * hv.w;
            p2 += a2.x * hv.x + a2.y * hv.y + a2.z * hv.z + a2.w * hv.w;
        }

        // butterfly reduce within 16-lane groups (offsets 1,2,4,8)
#pragma unroll
        for (int off = 1; off < 16; off <<= 1) {
            p0 += __shfl_xor(p0, off);
            p1 += __shfl_xor(p1, off);
            p2 += __shfl_xor(p2, off);
        }

        if (q == 0) {
            float hr = p0 + bh_r;
            float hz = p1 + bh_z;
            float hn = p2 + bh_n;
            float rg = 1.f / (1.f + __expf(-(xr + hr)));
            float zg = 1.f / (1.f + __expf(-(xz + hz)));
            float ng = fast_tanh(xn + rg * hn);
            float hnew = (1.f - zg) * ng + zg * hprev;
            bool valid = t < len_b;
            float hkeep = valid ? hnew : hprev;
            hprev = hkeep;
            // publish FIRST (gang-wide critical path): plain relaxed store
            if (t < Tdim - 1) {
                unsigned long long pv =
                    ((unsigned long long)(unsigned)(t + 1) << 32) |
                    (unsigned long long)__float_as_uint(hkeep);
                __hip_atomic_store(gslot + (size_t)((t + 1) & 1) * PSTR + j, pv,
                                   __ATOMIC_RELAXED, __HIP_MEMORY_SCOPE_AGENT);
            } else {
                h_last[b * Hdim + j] = hkeep;
            }
            float y = valid ? hnew : 0.f;
            unsigned short yh = f2bf(y);
            yh_buf[t][wave * 4 + g] = yh;
            yl_buf[t][wave * 4 + g] = f2bf(y - bf2f(yh));
        }
    }

    // coalesced block writeback of cat cols [blk*32, blk*32+32)
    __syncthreads();
    for (int idx = tid; idx < 64 * 16; idx += 512) {
        int t = idx >> 4, c = (idx & 15) * 2;
        size_t off = (size_t)(b * Tdim + t) * 1024 + blk * 32 + c;
        *(unsigned*)(cath + off) = *(const unsigned*)(&yh_buf[t][c]);
        *(unsigned*)(catl + off) = *(const unsigned*)(&yl_buf[t][c]);
    }
}

// ------------------------------ attention ----------------------------------
// one block per (b,d). Scoring loop vectorized (float4 encp loads; decp+
// battn and v_w staged once in LDS). Summation order identical to scalar.

__global__ __launch_bounds__(256) void attn_kernel(
    const float* __restrict__ encp,     // (1024,512)
    const float* __restrict__ decp,     // (1024,512)
    const float* __restrict__ enc,      // (16,64,512)
    const float* __restrict__ battn,    // (512)
    const float* __restrict__ vw,       // (512)
    const float* __restrict__ vb,       // (1)
    const int* __restrict__ enc_len,    // (16)
    const int* __restrict__ dec_len,    // (16)
    unsigned short* __restrict__ cath,
    unsigned short* __restrict__ catl)
{
    const int blk = blockIdx.x;
    const int b = blk >> 6, d = blk & 63;
    const int tid = threadIdx.x;
    const size_t obase = (size_t)(b * Tdim + d) * 1024 + 512;

    if (d >= dec_len[b]) {
        for (int h = tid; h < Hdim; h += 256) { cath[obase + h] = 0; catl[obase + h] = 0; }
        return;
    }
    const int Tv = enc_len[b];

    __shared__ float dpb[512];          // decp row + battn
    __shared__ float vwl[512];          // v_w
    __shared__ float part[64][4];
    __shared__ float a_lds[64];

    if (tid < 128) {
        const float4* dp4 = (const float4*)(decp + (size_t)(b * Tdim + d) * Hdim);
        float4 dv = dp4[tid];
        float4 bb = ((const float4*)battn)[tid];
        float4 r; r.x = dv.x + bb.x; r.y = dv.y + bb.y;
        r.z = dv.z + bb.z; r.w = dv.w + bb.w;
        ((float4*)dpb)[tid] = r;
        ((float4*)vwl)[tid] = ((const float4*)vw)[tid];
    }
    __syncthreads();

    const int e = tid >> 2, p = tid & 3;
    float s = 0.f;
    if (e < Tv) {
        const float4* ep4 = (const float4*)(encp + (size_t)(b * Tdim + e) * Hdim);
        const int q0 = p * 32;          // float4 index base (g0 = p*128)
        for (int q = q0; q < q0 + 32; ++q) {
            float4 ev = ep4[q];
            s += vwl[q * 4 + 0] * fast_tanh(ev.x + dpb[q * 4 + 0]);
            s += vwl[q * 4 + 1] * fast_tanh(ev.y + dpb[q * 4 + 1]);
            s += vwl[q * 4 + 2] * fast_tanh(ev.z + dpb[q * 4 + 2]);
            s += vwl[q * 4 + 3] * fast_tanh(ev.w + dpb[q * 4 + 3]);
        }
    }
    part[e][p] = s;
    __syncthreads();

    if (tid < 64) {
        const int e2 = tid;
        float en = (e2 < Tv) ? (part[e2][0] + part[e2][1] + part[e2][2] + part[e2][3] + vb[0]) : -1e30f;
        float m = en;
#pragma unroll
        for (int off = 32; off; off >>= 1) m = fmaxf(m, __shfl_xor(m, off));
        float ex = (e2 < Tv) ? __expf(en - m) : 0.f;
        float sum = ex;
#pragma unroll
        for (int off = 32; off; off >>= 1) sum += __shfl_xor(sum, off);
        a_lds[e2] = ex / sum;
    }
    __syncthreads();

    const int h = tid * 2;
    float c0 = 0.f, c1 = 0.f;
    for (int e3 = 0; e3 < Tv; ++e3) {
        float a = a_lds[e3];
        float2 ev = *(const float2*)(enc + (size_t)(b * Tdim + e3) * Hdim + h);
        c0 += a * ev.x; c1 += a * ev.y;
    }
    unsigned short h0 = f2bf(c0), h1 = f2bf(c1);
    cath[obase + h]     = h0;  catl[obase + h]     = f2bf(c0 - bf2f(h0));
    cath[obase + h + 1] = h1;  catl[obase + h + 1] = f2bf(c1 - bf2f(h1));
}

// --------------------------- logits bf16 MFMA GEMM -------------------------
// C(1024 x 32000) = A(1024x512 bf16) @ B(32000x512 bf16)^T + bias, fp32 out
// 256x256 tile, 512 threads (8 waves: 2m x 4n of 128x64 each).

__global__ __launch_bounds__(512) void gemm_logits(
    const unsigned short* __restrict__ A,
    const unsigned short* __restrict__ B,
    const float* __restrict__ bias,
    float* __restrict__ C)
{
    const int K = Hdim;
    __shared__ unsigned short As[256 * 40];
    __shared__ unsigned short Bs[256 * 40];
    const int tid = threadIdx.x;
    const int m0 = blockIdx.y * 256, n0 = blockIdx.x * 256;
    const int wave = tid >> 6, lane = tid & 63;
    const int wm = (wave >> 2) * 128, wn = (wave & 3) * 64;
    const int lrow = lane & 15, lk = (lane >> 4) * 8;

    f32x4 acc[8][4];
#pragma unroll
    for (int i = 0; i < 8; ++i)
#pragma unroll
        for (int j = 0; j < 4; ++j) acc[i][j] = (f32x4){0.f, 0.f, 0.f, 0.f};

    for (int k0 = 0; k0 < K; k0 += 32) {
#pragma unroll
        for (int i = 0; i < 2; ++i) {
            int idx = tid + i * 512;        // 0..1023
            int rr = idx >> 2, kq = (idx & 3) * 8;
            *(uint4*)(&As[rr * 40 + kq]) = *(const uint4*)(A + (size_t)(m0 + rr) * K + k0 + kq);
            *(uint4*)(&Bs[rr * 40 + kq]) = *(const uint4*)(B + (size_t)(n0 + rr) * K + k0 + kq);
        }
        __syncthreads();
        bf16x8 af[8], bf[4];
#pragma unroll
        for (int i = 0; i < 8; ++i) af[i] = *(const bf16x8*)(&As[(wm + i * 16 + lrow) * 40 + lk]);
#pragma unroll
        for (int j = 0; j < 4; ++j) bf[j] = *(const bf16x8*)(&Bs[(wn + j * 16 + lrow) * 40 + lk]);
#pragma unroll
        for (int i = 0; i < 8; ++i)
#pragma unroll
            for (int j = 0; j < 4; ++j)
                acc[i][j] = __builtin_amdgcn_mfma_f32_16x16x32_bf16(af[i], bf[j], acc[i][j], 0, 0, 0);
        __syncthreads();
    }

    const int crow = m0 + wm + ((lane >> 4) * 4);
    const int ccol = n0 + wn + (lane & 15);
#pragma unroll
    for (int i = 0; i < 8; ++i) {
#pragma unroll
        for (int j = 0; j < 4; ++j) {
            int col = ccol + j * 16;
            float bv = bias[col];
#pragma unroll
            for (int rr = 0; rr < 4; ++rr) {
                int row = crow + i * 16 + rr;
                C[(size_t)row * Vdim + col] = acc[i][j][rr] + bv;
            }
        }
    }
}

// ------------------------------- launcher ----------------------------------

extern "C" void kernel_launch(void* const* d_in, const int* in_sizes, int n_in,
                              void* d_out, int out_size, void* d_ws, size_t ws_size,
                              hipStream_t stream) {
    (void)in_sizes; (void)n_in; (void)out_size; (void)ws_size;

    const float* input_seqs  = (const float*)d_in[0];
    const int*   input_len   = (const int*)  d_in[1];
    const float* enc_out     = (const float*)d_in[2];
    const int*   enc_len     = (const int*)  d_in[3];
    const float* W_ih        = (const float*)d_in[4];
    const float* W_hh        = (const float*)d_in[5];
    const float* b_ih        = (const float*)d_in[6];
    const float* b_hh        = (const float*)d_in[7];
    const float* W_attn      = (const float*)d_in[8];
    const float* b_attn      = (const float*)d_in[9];
    const float* v_w         = (const float*)d_in[10];
    const float* v_b         = (const float*)d_in[11];
    const float* W_dense     = (const float*)d_in[12];
    const float* b_dense     = (const float*)d_in[13];
    const float* W_out       = (const float*)d_in[14];
    const float* b_out       = (const float*)d_in[15];

    float* logits = (float*)d_out;                        // (1024, 32000)
    float* h_last = (float*)d_out + (size_t)BT * Vdim;    // (16, 512)

    // ---- workspace layout ----
    float* ws    = (float*)d_ws;
    float* xp    = ws;                         // 1572864 f
    float* encp  = xp   + 1572864;             // 524288 f
    float* decp  = encp + 524288;              // 524288 f
    unsigned long long* hslots = (unsigned long long*)(decp + 524288); // 16384 u64
    float* zbias = (float*)(hslots + 16384);   // 512 f
    unsigned short* U0 = (unsigned short*)(zbias + 512);
    unsigned short* inp_h   = U0;               // 524288
    unsigned short* inp_l   = U0 + 524288;      // 524288
    unsigned short* Wih_h   = U0 + 1048576;     // 786432
    unsigned short* Wih_l   = U0 + 1835008;     // 786432
    unsigned short* Wattn_h = U0 + 2621440;     // 524288
    unsigned short* Wattn_l = U0 + 3145728;     // 524288
    unsigned short* Wden_h  = U0 + 3670016;     // 524288
    unsigned short* Wden_l  = U0 + 4194304;     // 524288
    unsigned short* enc_h   = U0 + 4718592;     // 524288
    unsigned short* enc_l   = U0 + 5242880;     // 524288
    unsigned short* Wout_bf = U0 + 5767168;     // 16384000
    // cat hi/lo alias the inp/Wih splits (dead after x_proj):
    unsigned short* cath = U0;                  // 1048576 (1024x1024)
    unsigned short* catl = U0 + 1048576;        // 1048576
    // dense_bf aliases encp (dead after attn):
    unsigned short* dense_bf = (unsigned short*)encp;   // 524288

    // 1. merged preprocessing (zero + splits + W_out cvt, full-grid)
    preproc_kernel<<<4096, 256, 0, stream>>>(
        input_seqs, W_ih, W_attn, W_dense, enc_out, W_out,
        (float*)hslots,
        inp_h, inp_l, Wih_h, Wih_l, Wattn_h, Wattn_l,
        Wden_h, Wden_l, enc_h, enc_l, Wout_bf);

    // 2. x_proj (1024x1536,K=512) + enc_p (1024x512,K=512) in ONE launch
    gemm_split_dual<<<128, 256, 0, stream>>>(
        inp_h, inp_l, Wih_h, Wih_l, b_ih, xp,
        enc_h, enc_l, Wattn_h, Wattn_l, zbias, encp);

    // 3. GRU (R6 protocol frozen; R14 short-reduce compute)
    gru_persistent<<<Bdim * GANG_BLOCKS, 512, 0, stream>>>(
        xp, W_hh, b_hh, input_len, hslots, cath, catl, h_last);

    // 4. dec_p = dec_out @ Wd^T (A = cat pair, lda=1024), no bias
    gemm_split<<<dim3(Hdim / 128, BT / 128), 256, 0, stream>>>(
        cath, catl, 1024, Wattn_h + 512, Wattn_l + 512, 1024, zbias, decp, nullptr, Hdim, Hdim, 0);

    // 5. attention -> cat cols [512,1024) hi/lo bf16 (vectorized scoring)
    attn_kernel<<<BT, 256, 0, stream>>>(encp, decp, enc_out, b_attn, v_w, v_b,
                                        enc_len, input_len, cath, catl);

    // 6. dense = tanh(cat @ W_dense^T + b_dense) -> bf16 directly (K=1024)
    gemm_split<<<dim3(Hdim / 128, BT / 128), 256, 0, stream>>>(
        cath, catl, 1024, Wden_h, Wden_l, 1024, b_dense, nullptr, dense_bf, Hdim, 1024, 1);

    // 7. logits = dense @ W_out^T + b_out  (1024 x 32000, K=512, 256x256)
    gemm_logits<<<dim3(Vdim / 256, BT / 256), 512, 0, stream>>>(
        dense_bf, Wout_bf, b_out, logits);
}

// Round 11
// 668.893 us; speedup vs baseline: 2.0843x; 2.0843x over previous
//
#include <hip/hip_runtime.h>
#include <stdint.h>

// ---------------------------------------------------------------------------
// Decoder: GRU(seq) + attention + dense + vocab projection
// H=512, V=32000, B=16, Td=Te=64
// Round 15 (base = R13 GRU + R14's 256x256 logits):
//  - R14 post-mortem: w4[3][8] indexed by runtime (c+q)&7 -> compiler
//    demoted to SCRATCH (VGPR 80->60, FETCH 25MB->1.7GB, GRU 279->1038us).
//    Rule #20: runtime-indexed register arrays go to local memory.
//    GRU REVERTED to exact R13 code (static w[12][8] indexing, transposed
//    LDS stage, 6-stage butterfly) = 279us, reproduced 6x. FROZEN, both
//    protocol AND compute layout.
//  - gemm_logits 256x256 KEPT (R14 non-GRU 356 vs R13 376: ~20us win).
//  - W_out f32->bf16 in the big preproc (R10 placement).
//  - Pair-operand GEMMs from precomputed hi/lo splits; attn vectorized.
//  - split-bf16 MFMA everywhere (AhBh+AhBl+AlBh, ~1.6e-5 rel err).
// Ledger: R13=655.6 (GRU 279 + non-GRU 376); R14 logits-256 = -20us.
// Predicted ~635.
// ---------------------------------------------------------------------------

#define Hdim 512
#define Vdim 32000
#define Bdim 16
#define Tdim 64
#define BT   1024   // B*Td rows
#define GANG_BLOCKS 16

typedef __attribute__((ext_vector_type(8))) short bf16x8;
typedef __attribute__((ext_vector_type(4))) float f32x4;

static __device__ __forceinline__ unsigned short f2bf(float f) {
    unsigned u = __float_as_uint(f);
    u = u + 0x7FFFu + ((u >> 16) & 1u);   // RNE
    return (unsigned short)(u >> 16);
}
static __device__ __forceinline__ float bf2f(unsigned short h) {
    return __uint_as_float((unsigned)h << 16);
}
static __device__ __forceinline__ float fast_tanh(float x) {
    return 2.f / (1.f + __expf(-2.f * x)) - 1.f;
}

// --------------------------- merged preprocessing --------------------------
// Zero hslots+zbias, five f32->(hi,lo) splits, W_out f32->bf16.

#define U_ZERO 8320      // (16384 u64 -> 32768 f) + 512 f zbias, /4
#define U_INP  131072    // 1024*512/4
#define U_WIH  196608    // 1536*512/4
#define U_WAT  131072    // 512*1024/4
#define U_WDE  131072    // 512*1024/4
#define U_ENC  131072    // 1024*512/4
#define U_SPLIT (U_INP + U_WIH + U_WAT + U_WDE + U_ENC)
#define U_WOUT 4096000   // 32000*512/4
#define U_TOT  (U_ZERO + U_SPLIT + U_WOUT)

__global__ __launch_bounds__(256) void preproc_kernel(
    const float* __restrict__ input_seqs,
    const float* __restrict__ W_ih,
    const float* __restrict__ W_attn,
    const float* __restrict__ W_dense,
    const float* __restrict__ enc,
    const float* __restrict__ W_out,
    float* __restrict__ zero_base,      // hslots..zbias, 33280 floats
    unsigned short* __restrict__ inp_h, unsigned short* __restrict__ inp_l,
    unsigned short* __restrict__ Wih_h, unsigned short* __restrict__ Wih_l,
    unsigned short* __restrict__ Wat_h, unsigned short* __restrict__ Wat_l,
    unsigned short* __restrict__ Wde_h, unsigned short* __restrict__ Wde_l,
    unsigned short* __restrict__ enc_h, unsigned short* __restrict__ enc_l,
    unsigned short* __restrict__ Wout_bf)
{
    int u = blockIdx.x * 256 + threadIdx.x;
    const int stride = gridDim.x * 256;
    for (; u < U_TOT; u += stride) {
        int r = u;
        if (r < U_ZERO) {
            float4 z; z.x = 0.f; z.y = 0.f; z.z = 0.f; z.w = 0.f;
            *(float4*)(zero_base + r * 4) = z;
            continue;
        }
        r -= U_ZERO;
        if (r >= U_SPLIT) {
            int i = (r - U_SPLIT) * 4;
            float4 v = *(const float4*)(W_out + i);
            unsigned short h[4] = {f2bf(v.x), f2bf(v.y), f2bf(v.z), f2bf(v.w)};
            *(uint2*)(Wout_bf + i) = *(const uint2*)h;
            continue;
        }
        const float* src; unsigned short* hi; unsigned short* lo;
        if (r < U_INP) { src = input_seqs; hi = inp_h; lo = inp_l; }
        else { r -= U_INP;
            if (r < U_WIH) { src = W_ih; hi = Wih_h; lo = Wih_l; }
            else { r -= U_WIH;
                if (r < U_WAT) { src = W_attn; hi = Wat_h; lo = Wat_l; }
                else { r -= U_WAT;
                    if (r < U_WDE) { src = W_dense; hi = Wde_h; lo = Wde_l; }
                    else { r -= U_WDE; src = enc; hi = enc_h; lo = enc_l; }
                }
            }
        }
        int i = r * 4;
        float4 v = *(const float4*)(src + i);
        float f[4] = {v.x, v.y, v.z, v.w};
        unsigned short h[4], l[4];
#pragma unroll
        for (int k = 0; k < 4; ++k) {
            h[k] = f2bf(f[k]);
            l[k] = f2bf(f[k] - bf2f(h[k]));
        }
        *(uint2*)(hi + i) = *(const uint2*)h;
        *(uint2*)(lo + i) = *(const uint2*)l;
    }
}

// ----------------------- split-bf16 MFMA GEMM body -------------------------

struct GemmSmem {
    unsigned short AsH[128 * 40];
    unsigned short AsL[128 * 40];
    unsigned short BsH[128 * 40];
    unsigned short BsL[128 * 40];
};

static __device__ __forceinline__ void gemm_tile(
    GemmSmem& S, int m0, int n0,
    const unsigned short* __restrict__ Ah, const unsigned short* __restrict__ Al, int lda,
    const unsigned short* __restrict__ Bh, const unsigned short* __restrict__ Bl, int ldb,
    const float* __restrict__ bias,
    float* __restrict__ C, unsigned short* __restrict__ Cb, int ldc,
    int K, int act)
{
    const int tid = threadIdx.x;
    const int wave = tid >> 6, lane = tid & 63;
    const int wm = (wave >> 1) * 64, wn = (wave & 1) * 64;
    const int lrow = lane & 15, lk = (lane >> 4) * 8;

    f32x4 acc[4][4];
#pragma unroll
    for (int i = 0; i < 4; ++i)
#pragma unroll
        for (int j = 0; j < 4; ++j) acc[i][j] = (f32x4){0.f, 0.f, 0.f, 0.f};

    for (int k0 = 0; k0 < K; k0 += 32) {
#pragma unroll
        for (int i = 0; i < 2; ++i) {
            int idx = tid + i * 256;        // 0..511
            int rr = idx >> 2, kq = (idx & 3) * 8;
            size_t ao = (size_t)(m0 + rr) * lda + k0 + kq;
            size_t bo = (size_t)(n0 + rr) * ldb + k0 + kq;
            *(uint4*)(&S.AsH[rr * 40 + kq]) = *(const uint4*)(Ah + ao);
            *(uint4*)(&S.AsL[rr * 40 + kq]) = *(const uint4*)(Al + ao);
            *(uint4*)(&S.BsH[rr * 40 + kq]) = *(const uint4*)(Bh + bo);
            *(uint4*)(&S.BsL[rr * 40 + kq]) = *(const uint4*)(Bl + bo);
        }
        __syncthreads();
        bf16x8 ah[4], al[4], bh[4], bl[4];
#pragma unroll
        for (int i = 0; i < 4; ++i) {
            ah[i] = *(const bf16x8*)(&S.AsH[(wm + i * 16 + lrow) * 40 + lk]);
            al[i] = *(const bf16x8*)(&S.AsL[(wm + i * 16 + lrow) * 40 + lk]);
        }
#pragma unroll
        for (int j = 0; j < 4; ++j) {
            bh[j] = *(const bf16x8*)(&S.BsH[(wn + j * 16 + lrow) * 40 + lk]);
            bl[j] = *(const bf16x8*)(&S.BsL[(wn + j * 16 + lrow) * 40 + lk]);
        }
#pragma unroll
        for (int i = 0; i < 4; ++i)
#pragma unroll
            for (int j = 0; j < 4; ++j) {
                acc[i][j] = __builtin_amdgcn_mfma_f32_16x16x32_bf16(ah[i], bh[j], acc[i][j], 0, 0, 0);
                acc[i][j] = __builtin_amdgcn_mfma_f32_16x16x32_bf16(ah[i], bl[j], acc[i][j], 0, 0, 0);
                acc[i][j] = __builtin_amdgcn_mfma_f32_16x16x32_bf16(al[i], bh[j], acc[i][j], 0, 0, 0);
            }
        __syncthreads();
    }

    const int crow = m0 + wm + ((lane >> 4) * 4);
    const int ccol = n0 + wn + (lane & 15);
#pragma unroll
    for (int i = 0; i < 4; ++i) {
#pragma unroll
        for (int j = 0; j < 4; ++j) {
            int col = ccol + j * 16;
            float bv = bias[col];
#pragma unroll
            for (int rr = 0; rr < 4; ++rr) {
                int row = crow + i * 16 + rr;
                float v = acc[i][j][rr] + bv;
                if (act == 1) v = fast_tanh(v);
                if (Cb) Cb[(size_t)row * ldc + col] = f2bf(v);
                else    C [(size_t)row * ldc + col] = v;
            }
        }
    }
}

// single-job GEMM (dec_p, dense)
__global__ __launch_bounds__(256) void gemm_split(
    const unsigned short* __restrict__ Ah, const unsigned short* __restrict__ Al, int lda,
    const unsigned short* __restrict__ Bh, const unsigned short* __restrict__ Bl, int ldb,
    const float* __restrict__ bias,
    float* __restrict__ C, unsigned short* __restrict__ Cb, int ldc,
    int K, int act)
{
    __shared__ GemmSmem S;
    gemm_tile(S, blockIdx.y * 128, blockIdx.x * 128,
              Ah, Al, lda, Bh, Bl, ldb, bias, C, Cb, ldc, K, act);
}

// dual-job GEMM: job A = x_proj (96 blocks), job B = enc_p (32 blocks)
__global__ __launch_bounds__(256) void gemm_split_dual(
    const unsigned short* __restrict__ A0h, const unsigned short* __restrict__ A0l,
    const unsigned short* __restrict__ B0h, const unsigned short* __restrict__ B0l,
    const float* __restrict__ bias0, float* __restrict__ C0,
    const unsigned short* __restrict__ A1h, const unsigned short* __restrict__ A1l,
    const unsigned short* __restrict__ B1h, const unsigned short* __restrict__ B1l,
    const float* __restrict__ bias1, float* __restrict__ C1)
{
    __shared__ GemmSmem S;
    const int bid = blockIdx.x;
    if (bid < 96) {
        gemm_tile(S, (bid / 12) * 128, (bid % 12) * 128,
                  A0h, A0l, Hdim, B0h, B0l, Hdim, bias0, C0, nullptr, 1536, Hdim, 0);
    } else {
        int r = bid - 96;
        gemm_tile(S, (r / 4) * 128, (r % 4) * 128,
                  A1h, A1l, Hdim, B1h, B1l, 1024, bias1, C1, nullptr, Hdim, Hdim, 0);
    }
}

// --------------------------- persistent GRU --------------------------------
// R6 topology + R13 compute, BOTH FROZEN (floor 4.3-4.4us/step, 6x repro;
// R14's "shorter reduce" hit rule #20 scratch demotion and regressed 3.7x).
// 16 gangs x 16 blocks x 512 thr. Block owns 32 units; wave w owns
// j0 = blk*32 + w*4 (12 W_hh rows in regs, STATIC indexing). h unit j
// parity p at hslots[p*8192 + b*512 + j] as (tag=t)<<32|bits. Wave 0 polls
// its 8 units/lane (tag==t), stages TRANSPOSED into LDS hl[par][q*64+lane]
// (conflict-free), one __syncthreads, all 8 waves compute. Publish = plain
// relaxed agent store. y buffered in LDS, coalesced writeback after loop.

__global__ __launch_bounds__(512) void gru_persistent(
    const float* __restrict__ xp,        // (1024,1536) rows = b*64+t
    const float* __restrict__ Whh,       // (1536,512)
    const float* __restrict__ bhh,       // (1536)
    const int*   __restrict__ lengths,   // (16)
    unsigned long long* __restrict__ hslots, // (2,16,512) tagged; zero-init
    unsigned short* __restrict__ cath,   // (1024,1024) cols [0,512)
    unsigned short* __restrict__ catl,
    float* __restrict__ h_last)          // (16,512)
{
    const int bid  = blockIdx.x;
    const int b    = bid >> 4;           // gang = batch
    const int blk  = bid & 15;
    const int tid  = threadIdx.x;
    const int wave = tid >> 6, lane = tid & 63;
    const int j0 = blk * 32 + wave * 4;  // this wave's 4 hidden units
    const int k0 = lane * 8;

    __shared__ float hl[2][512];                // transposed [q*64+lane]
    __shared__ unsigned short yh_buf[64][32];   // [t][unit-in-block] hi
    __shared__ unsigned short yl_buf[64][32];   // [t][unit-in-block] lo

    // --- W_hh slice into registers (once): 12 rows x 8 k-elems ---
    float w[12][8];
#pragma unroll
    for (int g = 0; g < 3; ++g)
#pragma unroll
        for (int jj = 0; jj < 4; ++jj) {
            const float* src = Whh + (size_t)(g * 512 + j0 + jj) * Hdim + k0;
            float4 a = *(const float4*)src;
            float4 bq = *(const float4*)(src + 4);
            int r = g * 4 + jj;
            w[r][0] = a.x;  w[r][1] = a.y;  w[r][2] = a.z;  w[r][3] = a.w;
            w[r][4] = bq.x; w[r][5] = bq.y; w[r][6] = bq.z; w[r][7] = bq.w;
        }

    const int j = j0 + (lane & 3);       // output unit for lanes 0..3
    float bh_r = 0.f, bh_z = 0.f, bh_n = 0.f;
    if (lane < 4) {
        bh_r = bhh[j]; bh_z = bhh[512 + j]; bh_n = bhh[1024 + j];
    }
    const int len_b = lengths[b];
    float hprev = 0.f;                   // this lane's own h[b][j] (h0 = 0)

    const size_t PSTR = (size_t)Bdim * Hdim;           // parity stride
    unsigned long long* gslot = hslots + (size_t)b * Hdim;
    const float* xbase = xp + (size_t)b * Tdim * 1536;

    for (int t = 0; t < Tdim; ++t) {
        const int par = t & 1;

        // xp loads are independent of h -> issue early
        float xr = 0.f, xz = 0.f, xn = 0.f;
        if (lane < 4) {
            const float* xrow = xbase + (size_t)t * 1536;
            xr = xrow[j]; xz = xrow[512 + j]; xn = xrow[1024 + j];
        }

        // wave 0: poll tagged slots (units lane*8 .. +7), stage transposed
        if (wave == 0) {
            const unsigned long long* sl = gslot + (size_t)par * PSTR + k0;
            unsigned long long v[8];
            bool ok;
            do {
#pragma unroll
                for (int q = 0; q < 8; ++q)
                    v[q] = __hip_atomic_load(sl + q, __ATOMIC_RELAXED,
                                             __HIP_MEMORY_SCOPE_AGENT);
                ok = true;
#pragma unroll
                for (int q = 0; q < 8; ++q)
                    ok = ok && ((unsigned)(v[q] >> 32) == (unsigned)t);
            } while (!ok);
#pragma unroll
            for (int q = 0; q < 8; ++q)   // unit lane*8+q -> [q*64+lane]
                hl[par][q * 64 + lane] = __uint_as_float((unsigned)v[q]);
        }
        __syncthreads();                  // SYNC_t: hl[par] ready

        float hv[8];
#pragma unroll
        for (int q = 0; q < 8; ++q) hv[q] = hl[par][q * 64 + lane];

        float p[12];
#pragma unroll
        for (int r = 0; r < 12; ++r) {
            float s = 0.f;
#pragma unroll
            for (int k = 0; k < 8; ++k) s += w[r][k] * hv[k];
            p[r] = s;
        }

        // butterfly reduce across 64 lanes
#pragma unroll
        for (int off = 1; off < 64; off <<= 1)
#pragma unroll
            for (int r = 0; r < 12; ++r)
                p[r] += __shfl_xor(p[r], off);

        if (lane < 4) {
            const int jj = lane;
            float hr = p[jj]     + bh_r;
            float hz = p[4 + jj] + bh_z;
            float hn = p[8 + jj] + bh_n;
            float rg = 1.f / (1.f + __expf(-(xr + hr)));
            float zg = 1.f / (1.f + __expf(-(xz + hz)));
            float ng = fast_tanh(xn + rg * hn);
            float hnew = (1.f - zg) * ng + zg * hprev;
            bool valid = t < len_b;
            float hkeep = valid ? hnew : hprev;
            hprev = hkeep;
            // publish FIRST (gang-wide critical path): plain relaxed store
            if (t < Tdim - 1) {
                unsigned long long pv =
                    ((unsigned long long)(unsigned)(t + 1) << 32) |
                    (unsigned long long)__float_as_uint(hkeep);
                __hip_atomic_store(gslot + (size_t)((t + 1) & 1) * PSTR + j, pv,
                                   __ATOMIC_RELAXED, __HIP_MEMORY_SCOPE_AGENT);
            } else {
                h_last[b * Hdim + j] = hkeep;
            }
            float y = valid ? hnew : 0.f;
            unsigned short yh = f2bf(y);
            yh_buf[t][wave * 4 + jj] = yh;
            yl_buf[t][wave * 4 + jj] = f2bf(y - bf2f(yh));
        }
    }

    // coalesced block writeback of cat cols [blk*32, blk*32+32)
    __syncthreads();
    for (int idx = tid; idx < 64 * 16; idx += 512) {
        int t = idx >> 4, c = (idx & 15) * 2;
        size_t off = (size_t)(b * Tdim + t) * 1024 + blk * 32 + c;
        *(unsigned*)(cath + off) = *(const unsigned*)(&yh_buf[t][c]);
        *(unsigned*)(catl + off) = *(const unsigned*)(&yl_buf[t][c]);
    }
}

// ------------------------------ attention ----------------------------------
// one block per (b,d). Scoring loop vectorized (float4 encp loads; decp+
// battn and v_w staged once in LDS). Summation order identical to scalar.

__global__ __launch_bounds__(256) void attn_kernel(
    const float* __restrict__ encp,     // (1024,512)
    const float* __restrict__ decp,     // (1024,512)
    const float* __restrict__ enc,      // (16,64,512)
    const float* __restrict__ battn,    // (512)
    const float* __restrict__ vw,       // (512)
    const float* __restrict__ vb,       // (1)
    const int* __restrict__ enc_len,    // (16)
    const int* __restrict__ dec_len,    // (16)
    unsigned short* __restrict__ cath,
    unsigned short* __restrict__ catl)
{
    const int blk = blockIdx.x;
    const int b = blk >> 6, d = blk & 63;
    const int tid = threadIdx.x;
    const size_t obase = (size_t)(b * Tdim + d) * 1024 + 512;

    if (d >= dec_len[b]) {
        for (int h = tid; h < Hdim; h += 256) { cath[obase + h] = 0; catl[obase + h] = 0; }
        return;
    }
    const int Tv = enc_len[b];

    __shared__ float dpb[512];          // decp row + battn
    __shared__ float vwl[512];          // v_w
    __shared__ float part[64][4];
    __shared__ float a_lds[64];

    if (tid < 128) {
        const float4* dp4 = (const float4*)(decp + (size_t)(b * Tdim + d) * Hdim);
        float4 dv = dp4[tid];
        float4 bb = ((const float4*)battn)[tid];
        float4 r; r.x = dv.x + bb.x; r.y = dv.y + bb.y;
        r.z = dv.z + bb.z; r.w = dv.w + bb.w;
        ((float4*)dpb)[tid] = r;
        ((float4*)vwl)[tid] = ((const float4*)vw)[tid];
    }
    __syncthreads();

    const int e = tid >> 2, p = tid & 3;
    float s = 0.f;
    if (e < Tv) {
        const float4* ep4 = (const float4*)(encp + (size_t)(b * Tdim + e) * Hdim);
        const int q0 = p * 32;          // float4 index base (g0 = p*128)
        for (int q = q0; q < q0 + 32; ++q) {
            float4 ev = ep4[q];
            s += vwl[q * 4 + 0] * fast_tanh(ev.x + dpb[q * 4 + 0]);
            s += vwl[q * 4 + 1] * fast_tanh(ev.y + dpb[q * 4 + 1]);
            s += vwl[q * 4 + 2] * fast_tanh(ev.z + dpb[q * 4 + 2]);
            s += vwl[q * 4 + 3] * fast_tanh(ev.w + dpb[q * 4 + 3]);
        }
    }
    part[e][p] = s;
    __syncthreads();

    if (tid < 64) {
        const int e2 = tid;
        float en = (e2 < Tv) ? (part[e2][0] + part[e2][1] + part[e2][2] + part[e2][3] + vb[0]) : -1e30f;
        float m = en;
#pragma unroll
        for (int off = 32; off; off >>= 1) m = fmaxf(m, __shfl_xor(m, off));
        float ex = (e2 < Tv) ? __expf(en - m) : 0.f;
        float sum = ex;
#pragma unroll
        for (int off = 32; off; off >>= 1) sum += __shfl_xor(sum, off);
        a_lds[e2] = ex / sum;
    }
    __syncthreads();

    const int h = tid * 2;
    float c0 = 0.f, c1 = 0.f;
    for (int e3 = 0; e3 < Tv; ++e3) {
        float a = a_lds[e3];
        float2 ev = *(const float2*)(enc + (size_t)(b * Tdim + e3) * Hdim + h);
        c0 += a * ev.x; c1 += a * ev.y;
    }
    unsigned short h0 = f2bf(c0), h1 = f2bf(c1);
    cath[obase + h]     = h0;  catl[obase + h]     = f2bf(c0 - bf2f(h0));
    cath[obase + h + 1] = h1;  catl[obase + h + 1] = f2bf(c1 - bf2f(h1));
}

// --------------------------- logits bf16 MFMA GEMM -------------------------
// C(1024 x 32000) = A(1024x512 bf16) @ B(32000x512 bf16)^T + bias, fp32 out
// 256x256 tile, 512 threads (8 waves: 2m x 4n of 128x64 each).

__global__ __launch_bounds__(512) void gemm_logits(
    const unsigned short* __restrict__ A,
    const unsigned short* __restrict__ B,
    const float* __restrict__ bias,
    float* __restrict__ C)
{
    const int K = Hdim;
    __shared__ unsigned short As[256 * 40];
    __shared__ unsigned short Bs[256 * 40];
    const int tid = threadIdx.x;
    const int m0 = blockIdx.y * 256, n0 = blockIdx.x * 256;
    const int wave = tid >> 6, lane = tid & 63;
    const int wm = (wave >> 2) * 128, wn = (wave & 3) * 64;
    const int lrow = lane & 15, lk = (lane >> 4) * 8;

    f32x4 acc[8][4];
#pragma unroll
    for (int i = 0; i < 8; ++i)
#pragma unroll
        for (int j = 0; j < 4; ++j) acc[i][j] = (f32x4){0.f, 0.f, 0.f, 0.f};

    for (int k0 = 0; k0 < K; k0 += 32) {
#pragma unroll
        for (int i = 0; i < 2; ++i) {
            int idx = tid + i * 512;        // 0..1023
            int rr = idx >> 2, kq = (idx & 3) * 8;
            *(uint4*)(&As[rr * 40 + kq]) = *(const uint4*)(A + (size_t)(m0 + rr) * K + k0 + kq);
            *(uint4*)(&Bs[rr * 40 + kq]) = *(const uint4*)(B + (size_t)(n0 + rr) * K + k0 + kq);
        }
        __syncthreads();
        bf16x8 af[8], bf[4];
#pragma unroll
        for (int i = 0; i < 8; ++i) af[i] = *(const bf16x8*)(&As[(wm + i * 16 + lrow) * 40 + lk]);
#pragma unroll
        for (int j = 0; j < 4; ++j) bf[j] = *(const bf16x8*)(&Bs[(wn + j * 16 + lrow) * 40 + lk]);
#pragma unroll
        for (int i = 0; i < 8; ++i)
#pragma unroll
            for (int j = 0; j < 4; ++j)
                acc[i][j] = __builtin_amdgcn_mfma_f32_16x16x32_bf16(af[i], bf[j], acc[i][j], 0, 0, 0);
        __syncthreads();
    }

    const int crow = m0 + wm + ((lane >> 4) * 4);
    const int ccol = n0 + wn + (lane & 15);
#pragma unroll
    for (int i = 0; i < 8; ++i) {
#pragma unroll
        for (int j = 0; j < 4; ++j) {
            int col = ccol + j * 16;
            float bv = bias[col];
#pragma unroll
            for (int rr = 0; rr < 4; ++rr) {
                int row = crow + i * 16 + rr;
                C[(size_t)row * Vdim + col] = acc[i][j][rr] + bv;
            }
        }
    }
}

// ------------------------------- launcher ----------------------------------

extern "C" void kernel_launch(void* const* d_in, const int* in_sizes, int n_in,
                              void* d_out, int out_size, void* d_ws, size_t ws_size,
                              hipStream_t stream) {
    (void)in_sizes; (void)n_in; (void)out_size; (void)ws_size;

    const float* input_seqs  = (const float*)d_in[0];
    const int*   input_len   = (const int*)  d_in[1];
    const float* enc_out     = (const float*)d_in[2];
    const int*   enc_len     = (const int*)  d_in[3];
    const float* W_ih        = (const float*)d_in[4];
    const float* W_hh        = (const float*)d_in[5];
    const float* b_ih        = (const float*)d_in[6];
    const float* b_hh        = (const float*)d_in[7];
    const float* W_attn      = (const float*)d_in[8];
    const float* b_attn      = (const float*)d_in[9];
    const float* v_w         = (const float*)d_in[10];
    const float* v_b         = (const float*)d_in[11];
    const float* W_dense     = (const float*)d_in[12];
    const float* b_dense     = (const float*)d_in[13];
    const float* W_out       = (const float*)d_in[14];
    const float* b_out       = (const float*)d_in[15];

    float* logits = (float*)d_out;                        // (1024, 32000)
    float* h_last = (float*)d_out + (size_t)BT * Vdim;    // (16, 512)

    // ---- workspace layout ----
    float* ws    = (float*)d_ws;
    float* xp    = ws;                         // 1572864 f
    float* encp  = xp   + 1572864;             // 524288 f
    float* decp  = encp + 524288;              // 524288 f
    unsigned long long* hslots = (unsigned long long*)(decp + 524288); // 16384 u64
    float* zbias = (float*)(hslots + 16384);   // 512 f
    unsigned short* U0 = (unsigned short*)(zbias + 512);
    unsigned short* inp_h   = U0;               // 524288
    unsigned short* inp_l   = U0 + 524288;      // 524288
    unsigned short* Wih_h   = U0 + 1048576;     // 786432
    unsigned short* Wih_l   = U0 + 1835008;     // 786432
    unsigned short* Wattn_h = U0 + 2621440;     // 524288
    unsigned short* Wattn_l = U0 + 3145728;     // 524288
    unsigned short* Wden_h  = U0 + 3670016;     // 524288
    unsigned short* Wden_l  = U0 + 4194304;     // 524288
    unsigned short* enc_h   = U0 + 4718592;     // 524288
    unsigned short* enc_l   = U0 + 5242880;     // 524288
    unsigned short* Wout_bf = U0 + 5767168;     // 16384000
    // cat hi/lo alias the inp/Wih splits (dead after x_proj):
    unsigned short* cath = U0;                  // 1048576 (1024x1024)
    unsigned short* catl = U0 + 1048576;        // 1048576
    // dense_bf aliases encp (dead after attn):
    unsigned short* dense_bf = (unsigned short*)encp;   // 524288

    // 1. merged preprocessing (zero + splits + W_out cvt, full-grid)
    preproc_kernel<<<4096, 256, 0, stream>>>(
        input_seqs, W_ih, W_attn, W_dense, enc_out, W_out,
        (float*)hslots,
        inp_h, inp_l, Wih_h, Wih_l, Wattn_h, Wattn_l,
        Wden_h, Wden_l, enc_h, enc_l, Wout_bf);

    // 2. x_proj (1024x1536,K=512) + enc_p (1024x512,K=512) in ONE launch
    gemm_split_dual<<<128, 256, 0, stream>>>(
        inp_h, inp_l, Wih_h, Wih_l, b_ih, xp,
        enc_h, enc_l, Wattn_h, Wattn_l, zbias, encp);

    // 3. GRU (R6 protocol + R13 compute, both frozen)
    gru_persistent<<<Bdim * GANG_BLOCKS, 512, 0, stream>>>(
        xp, W_hh, b_hh, input_len, hslots, cath, catl, h_last);

    // 4. dec_p = dec_out @ Wd^T (A = cat pair, lda=1024), no bias
    gemm_split<<<dim3(Hdim / 128, BT / 128), 256, 0, stream>>>(
        cath, catl, 1024, Wattn_h + 512, Wattn_l + 512, 1024, zbias, decp, nullptr, Hdim, Hdim, 0);

    // 5. attention -> cat cols [512,1024) hi/lo bf16 (vectorized scoring)
    attn_kernel<<<BT, 256, 0, stream>>>(encp, decp, enc_out, b_attn, v_w, v_b,
                                        enc_len, input_len, cath, catl);

    // 6. dense = tanh(cat @ W_dense^T + b_dense) -> bf16 directly (K=1024)
    gemm_split<<<dim3(Hdim / 128, BT / 128), 256, 0, stream>>>(
        cath, catl, 1024, Wden_h, Wden_l, 1024, b_dense, nullptr, dense_bf, Hdim, 1024, 1);

    // 7. logits = dense @ W_out^T + b_out  (1024 x 32000, K=512, 256x256)
    gemm_logits<<<dim3(Vdim / 256, BT / 256), 512, 0, stream>>>(
        dense_bf, Wout_bf, b_out, logits);
}

// Round 12
// 659.607 us; speedup vs baseline: 2.1136x; 1.0141x over previous
//
#include <hip/hip_runtime.h>
#include <stdint.h>

// ---------------------------------------------------------------------------
// Decoder: GRU(seq) + attention + dense + vocab projection
// H=512, V=32000, B=16, Td=Te=64
// Round 16 (base = R13, 655.6us best):
//  - R15 post-mortem: 256x256 logits was ~11us WORSE than 256x128 in a
//    clean A/B (R13 vs R15, same GRU). The R14 "-20us" was a cross-probe
//    inference from a corrupted run. gemm_logits REVERTED to R13 256x128.
//  - W_out f32->bf16 moved from preproc into the dec_p launch as 224
//    filler blocks: dec_p is a 32-block GEMM -> 224 CUs idle; its operands
//    (cat 4MB, Wattn 2MB) are L2-resident, insulated from the cvt's HBM
//    traffic. R11-lesson-compliant overlap (bulk BW under an idle-machine
//    throughput kernel, NOT the latency-bound GRU). Stream order
//    guarantees Wout_bf ready before gemm_logits. Preproc: 166MB -> 23MB.
//  - GRU: R6 protocol + R13 compute, BOTH FROZEN (4.3-4.4us/step, 7x
//    repro; R14's runtime-indexed regs hit rule-#20 scratch demotion).
//  - Pair-operand GEMMs from precomputed hi/lo splits; attn vectorized.
//  - split-bf16 MFMA everywhere (AhBh+AhBl+AlBh, ~1.6e-5 rel err).
// ---------------------------------------------------------------------------

#define Hdim 512
#define Vdim 32000
#define Bdim 16
#define Tdim 64
#define BT   1024   // B*Td rows
#define GANG_BLOCKS 16

typedef __attribute__((ext_vector_type(8))) short bf16x8;
typedef __attribute__((ext_vector_type(4))) float f32x4;

static __device__ __forceinline__ unsigned short f2bf(float f) {
    unsigned u = __float_as_uint(f);
    u = u + 0x7FFFu + ((u >> 16) & 1u);   // RNE
    return (unsigned short)(u >> 16);
}
static __device__ __forceinline__ float bf2f(unsigned short h) {
    return __uint_as_float((unsigned)h << 16);
}
static __device__ __forceinline__ float fast_tanh(float x) {
    return 2.f / (1.f + __expf(-2.f * x)) - 1.f;
}

// --------------------------- merged preprocessing --------------------------
// Zero hslots+zbias, five f32->(hi,lo) splits. (W_out cvt rides the dec_p
// launch's idle CUs.)

#define U_ZERO 8320      // (16384 u64 -> 32768 f) + 512 f zbias, /4
#define U_INP  131072    // 1024*512/4
#define U_WIH  196608    // 1536*512/4
#define U_WAT  131072    // 512*1024/4
#define U_WDE  131072    // 512*1024/4
#define U_ENC  131072    // 1024*512/4
#define U_SPLIT (U_INP + U_WIH + U_WAT + U_WDE + U_ENC)
#define U_TOT  (U_ZERO + U_SPLIT)   // 729216

__global__ __launch_bounds__(256) void preproc_kernel(
    const float* __restrict__ input_seqs,
    const float* __restrict__ W_ih,
    const float* __restrict__ W_attn,
    const float* __restrict__ W_dense,
    const float* __restrict__ enc,
    float* __restrict__ zero_base,      // hslots..zbias, 33280 floats
    unsigned short* __restrict__ inp_h, unsigned short* __restrict__ inp_l,
    unsigned short* __restrict__ Wih_h, unsigned short* __restrict__ Wih_l,
    unsigned short* __restrict__ Wat_h, unsigned short* __restrict__ Wat_l,
    unsigned short* __restrict__ Wde_h, unsigned short* __restrict__ Wde_l,
    unsigned short* __restrict__ enc_h, unsigned short* __restrict__ enc_l)
{
    int u = blockIdx.x * 256 + threadIdx.x;
    const int stride = gridDim.x * 256;
    for (; u < U_TOT; u += stride) {
        int r = u;
        if (r < U_ZERO) {
            float4 z; z.x = 0.f; z.y = 0.f; z.z = 0.f; z.w = 0.f;
            *(float4*)(zero_base + r * 4) = z;
            continue;
        }
        r -= U_ZERO;
        const float* src; unsigned short* hi; unsigned short* lo;
        if (r < U_INP) { src = input_seqs; hi = inp_h; lo = inp_l; }
        else { r -= U_INP;
            if (r < U_WIH) { src = W_ih; hi = Wih_h; lo = Wih_l; }
            else { r -= U_WIH;
                if (r < U_WAT) { src = W_attn; hi = Wat_h; lo = Wat_l; }
                else { r -= U_WAT;
                    if (r < U_WDE) { src = W_dense; hi = Wde_h; lo = Wde_l; }
                    else { r -= U_WDE; src = enc; hi = enc_h; lo = enc_l; }
                }
            }
        }
        int i = r * 4;
        float4 v = *(const float4*)(src + i);
        float f[4] = {v.x, v.y, v.z, v.w};
        unsigned short h[4], l[4];
#pragma unroll
        for (int k = 0; k < 4; ++k) {
            h[k] = f2bf(f[k]);
            l[k] = f2bf(f[k] - bf2f(h[k]));
        }
        *(uint2*)(hi + i) = *(const uint2*)h;
        *(uint2*)(lo + i) = *(const uint2*)l;
    }
}

// ----------------------- split-bf16 MFMA GEMM body -------------------------

struct GemmSmem {
    unsigned short AsH[128 * 40];
    unsigned short AsL[128 * 40];
    unsigned short BsH[128 * 40];
    unsigned short BsL[128 * 40];
};

static __device__ __forceinline__ void gemm_tile(
    GemmSmem& S, int m0, int n0,
    const unsigned short* __restrict__ Ah, const unsigned short* __restrict__ Al, int lda,
    const unsigned short* __restrict__ Bh, const unsigned short* __restrict__ Bl, int ldb,
    const float* __restrict__ bias,
    float* __restrict__ C, unsigned short* __restrict__ Cb, int ldc,
    int K, int act)
{
    const int tid = threadIdx.x;
    const int wave = tid >> 6, lane = tid & 63;
    const int wm = (wave >> 1) * 64, wn = (wave & 1) * 64;
    const int lrow = lane & 15, lk = (lane >> 4) * 8;

    f32x4 acc[4][4];
#pragma unroll
    for (int i = 0; i < 4; ++i)
#pragma unroll
        for (int j = 0; j < 4; ++j) acc[i][j] = (f32x4){0.f, 0.f, 0.f, 0.f};

    for (int k0 = 0; k0 < K; k0 += 32) {
#pragma unroll
        for (int i = 0; i < 2; ++i) {
            int idx = tid + i * 256;        // 0..511
            int rr = idx >> 2, kq = (idx & 3) * 8;
            size_t ao = (size_t)(m0 + rr) * lda + k0 + kq;
            size_t bo = (size_t)(n0 + rr) * ldb + k0 + kq;
            *(uint4*)(&S.AsH[rr * 40 + kq]) = *(const uint4*)(Ah + ao);
            *(uint4*)(&S.AsL[rr * 40 + kq]) = *(const uint4*)(Al + ao);
            *(uint4*)(&S.BsH[rr * 40 + kq]) = *(const uint4*)(Bh + bo);
            *(uint4*)(&S.BsL[rr * 40 + kq]) = *(const uint4*)(Bl + bo);
        }
        __syncthreads();
        bf16x8 ah[4], al[4], bh[4], bl[4];
#pragma unroll
        for (int i = 0; i < 4; ++i) {
            ah[i] = *(const bf16x8*)(&S.AsH[(wm + i * 16 + lrow) * 40 + lk]);
            al[i] = *(const bf16x8*)(&S.AsL[(wm + i * 16 + lrow) * 40 + lk]);
        }
#pragma unroll
        for (int j = 0; j < 4; ++j) {
            bh[j] = *(const bf16x8*)(&S.BsH[(wn + j * 16 + lrow) * 40 + lk]);
            bl[j] = *(const bf16x8*)(&S.BsL[(wn + j * 16 + lrow) * 40 + lk]);
        }
#pragma unroll
        for (int i = 0; i < 4; ++i)
#pragma unroll
            for (int j = 0; j < 4; ++j) {
                acc[i][j] = __builtin_amdgcn_mfma_f32_16x16x32_bf16(ah[i], bh[j], acc[i][j], 0, 0, 0);
                acc[i][j] = __builtin_amdgcn_mfma_f32_16x16x32_bf16(ah[i], bl[j], acc[i][j], 0, 0, 0);
                acc[i][j] = __builtin_amdgcn_mfma_f32_16x16x32_bf16(al[i], bh[j], acc[i][j], 0, 0, 0);
            }
        __syncthreads();
    }

    const int crow = m0 + wm + ((lane >> 4) * 4);
    const int ccol = n0 + wn + (lane & 15);
#pragma unroll
    for (int i = 0; i < 4; ++i) {
#pragma unroll
        for (int j = 0; j < 4; ++j) {
            int col = ccol + j * 16;
            float bv = bias[col];
#pragma unroll
            for (int rr = 0; rr < 4; ++rr) {
                int row = crow + i * 16 + rr;
                float v = acc[i][j][rr] + bv;
                if (act == 1) v = fast_tanh(v);
                if (Cb) Cb[(size_t)row * ldc + col] = f2bf(v);
                else    C [(size_t)row * ldc + col] = v;
            }
        }
    }
}

// single-job GEMM (dense)
__global__ __launch_bounds__(256) void gemm_split(
    const unsigned short* __restrict__ Ah, const unsigned short* __restrict__ Al, int lda,
    const unsigned short* __restrict__ Bh, const unsigned short* __restrict__ Bl, int ldb,
    const float* __restrict__ bias,
    float* __restrict__ C, unsigned short* __restrict__ Cb, int ldc,
    int K, int act)
{
    __shared__ GemmSmem S;
    gemm_tile(S, blockIdx.y * 128, blockIdx.x * 128,
              Ah, Al, lda, Bh, Bl, ldb, bias, C, Cb, ldc, K, act);
}

// dual-job GEMM: job A = x_proj (96 blocks), job B = enc_p (32 blocks)
__global__ __launch_bounds__(256) void gemm_split_dual(
    const unsigned short* __restrict__ A0h, const unsigned short* __restrict__ A0l,
    const unsigned short* __restrict__ B0h, const unsigned short* __restrict__ B0l,
    const float* __restrict__ bias0, float* __restrict__ C0,
    const unsigned short* __restrict__ A1h, const unsigned short* __restrict__ A1l,
    const unsigned short* __restrict__ B1h, const unsigned short* __restrict__ B1l,
    const float* __restrict__ bias1, float* __restrict__ C1)
{
    __shared__ GemmSmem S;
    const int bid = blockIdx.x;
    if (bid < 96) {
        gemm_tile(S, (bid / 12) * 128, (bid % 12) * 128,
                  A0h, A0l, Hdim, B0h, B0l, Hdim, bias0, C0, nullptr, 1536, Hdim, 0);
    } else {
        int r = bid - 96;
        gemm_tile(S, (r / 4) * 128, (r % 4) * 128,
                  A1h, A1l, Hdim, B1h, B1l, 1024, bias1, C1, nullptr, Hdim, Hdim, 0);
    }
}

// dec_p GEMM (32 blocks) + W_out f32->bf16 cvt (224 filler blocks).
// dec_p's operands are L2-resident (cat 4MB, Wattn 2MB) -> insulated from
// the cvt's HBM traffic; the cvt rides the 224 otherwise-idle CUs.
__global__ __launch_bounds__(256) void gemm_decp_cvt(
    const unsigned short* __restrict__ Ah, const unsigned short* __restrict__ Al,
    const unsigned short* __restrict__ Bh, const unsigned short* __restrict__ Bl,
    const float* __restrict__ bias,
    float* __restrict__ C,
    const float* __restrict__ Wout_f,      // (32000,512) f32
    unsigned short* __restrict__ Wout_bf)
{
    const int bid = blockIdx.x;
    if (bid >= 32) {
        // cvt: 4 consecutive float4 units per thread-iter (64B/lane, MLP=4)
        const int NG = (Vdim * Hdim) / 16;          // groups of 4 units
        int g = (bid - 32) * 256 + threadIdx.x;
        const int stride = 224 * 256;
        for (; g < NG; g += stride) {
#pragma unroll
            for (int c = 0; c < 4; ++c) {
                size_t u = (size_t)g * 4 + c;
                float4 v = *(const float4*)(Wout_f + u * 4);
                unsigned short h[4] = {f2bf(v.x), f2bf(v.y), f2bf(v.z), f2bf(v.w)};
                *(uint2*)(Wout_bf + u * 4) = *(const uint2*)h;
            }
        }
        return;
    }
    __shared__ GemmSmem S;
    gemm_tile(S, (bid >> 2) * 128, (bid & 3) * 128,
              Ah, Al, 1024, Bh, Bl, 1024, bias, C, nullptr, Hdim, Hdim, 0);
}

// --------------------------- persistent GRU --------------------------------
// R6 topology + R13 compute, BOTH FROZEN (floor 4.3-4.4us/step, 7x repro).
// 16 gangs x 16 blocks x 512 thr. Block owns 32 units; wave w owns
// j0 = blk*32 + w*4 (12 W_hh rows in regs, STATIC indexing). h unit j
// parity p at hslots[p*8192 + b*512 + j] as (tag=t)<<32|bits. Wave 0 polls
// its 8 units/lane (tag==t), stages TRANSPOSED into LDS hl[par][q*64+lane]
// (conflict-free), one __syncthreads, all 8 waves compute. Publish = plain
// relaxed agent store. y buffered in LDS, coalesced writeback after loop.

__global__ __launch_bounds__(512) void gru_persistent(
    const float* __restrict__ xp,        // (1024,1536) rows = b*64+t
    const float* __restrict__ Whh,       // (1536,512)
    const float* __restrict__ bhh,       // (1536)
    const int*   __restrict__ lengths,   // (16)
    unsigned long long* __restrict__ hslots, // (2,16,512) tagged; zero-init
    unsigned short* __restrict__ cath,   // (1024,1024) cols [0,512)
    unsigned short* __restrict__ catl,
    float* __restrict__ h_last)          // (16,512)
{
    const int bid  = blockIdx.x;
    const int b    = bid >> 4;           // gang = batch
    const int blk  = bid & 15;
    const int tid  = threadIdx.x;
    const int wave = tid >> 6, lane = tid & 63;
    const int j0 = blk * 32 + wave * 4;  // this wave's 4 hidden units
    const int k0 = lane * 8;

    __shared__ float hl[2][512];                // transposed [q*64+lane]
    __shared__ unsigned short yh_buf[64][32];   // [t][unit-in-block] hi
    __shared__ unsigned short yl_buf[64][32];   // [t][unit-in-block] lo

    // --- W_hh slice into registers (once): 12 rows x 8 k-elems ---
    float w[12][8];
#pragma unroll
    for (int g = 0; g < 3; ++g)
#pragma unroll
        for (int jj = 0; jj < 4; ++jj) {
            const float* src = Whh + (size_t)(g * 512 + j0 + jj) * Hdim + k0;
            float4 a = *(const float4*)src;
            float4 bq = *(const float4*)(src + 4);
            int r = g * 4 + jj;
            w[r][0] = a.x;  w[r][1] = a.y;  w[r][2] = a.z;  w[r][3] = a.w;
            w[r][4] = bq.x; w[r][5] = bq.y; w[r][6] = bq.z; w[r][7] = bq.w;
        }

    const int j = j0 + (lane & 3);       // output unit for lanes 0..3
    float bh_r = 0.f, bh_z = 0.f, bh_n = 0.f;
    if (lane < 4) {
        bh_r = bhh[j]; bh_z = bhh[512 + j]; bh_n = bhh[1024 + j];
    }
    const int len_b = lengths[b];
    float hprev = 0.f;                   // this lane's own h[b][j] (h0 = 0)

    const size_t PSTR = (size_t)Bdim * Hdim;           // parity stride
    unsigned long long* gslot = hslots + (size_t)b * Hdim;
    const float* xbase = xp + (size_t)b * Tdim * 1536;

    for (int t = 0; t < Tdim; ++t) {
        const int par = t & 1;

        // xp loads are independent of h -> issue early
        float xr = 0.f, xz = 0.f, xn = 0.f;
        if (lane < 4) {
            const float* xrow = xbase + (size_t)t * 1536;
            xr = xrow[j]; xz = xrow[512 + j]; xn = xrow[1024 + j];
        }

        // wave 0: poll tagged slots (units lane*8 .. +7), stage transposed
        if (wave == 0) {
            const unsigned long long* sl = gslot + (size_t)par * PSTR + k0;
            unsigned long long v[8];
            bool ok;
            do {
#pragma unroll
                for (int q = 0; q < 8; ++q)
                    v[q] = __hip_atomic_load(sl + q, __ATOMIC_RELAXED,
                                             __HIP_MEMORY_SCOPE_AGENT);
                ok = true;
#pragma unroll
                for (int q = 0; q < 8; ++q)
                    ok = ok && ((unsigned)(v[q] >> 32) == (unsigned)t);
            } while (!ok);
#pragma unroll
            for (int q = 0; q < 8; ++q)   // unit lane*8+q -> [q*64+lane]
                hl[par][q * 64 + lane] = __uint_as_float((unsigned)v[q]);
        }
        __syncthreads();                  // SYNC_t: hl[par] ready

        float hv[8];
#pragma unroll
        for (int q = 0; q < 8; ++q) hv[q] = hl[par][q * 64 + lane];

        float p[12];
#pragma unroll
        for (int r = 0; r < 12; ++r) {
            float s = 0.f;
#pragma unroll
            for (int k = 0; k < 8; ++k) s += w[r][k] * hv[k];
            p[r] = s;
        }

        // butterfly reduce across 64 lanes
#pragma unroll
        for (int off = 1; off < 64; off <<= 1)
#pragma unroll
            for (int r = 0; r < 12; ++r)
                p[r] += __shfl_xor(p[r], off);

        if (lane < 4) {
            const int jj = lane;
            float hr = p[jj]     + bh_r;
            float hz = p[4 + jj] + bh_z;
            float hn = p[8 + jj] + bh_n;
            float rg = 1.f / (1.f + __expf(-(xr + hr)));
            float zg = 1.f / (1.f + __expf(-(xz + hz)));
            float ng = fast_tanh(xn + rg * hn);
            float hnew = (1.f - zg) * ng + zg * hprev;
            bool valid = t < len_b;
            float hkeep = valid ? hnew : hprev;
            hprev = hkeep;
            // publish FIRST (gang-wide critical path): plain relaxed store
            if (t < Tdim - 1) {
                unsigned long long pv =
                    ((unsigned long long)(unsigned)(t + 1) << 32) |
                    (unsigned long long)__float_as_uint(hkeep);
                __hip_atomic_store(gslot + (size_t)((t + 1) & 1) * PSTR + j, pv,
                                   __ATOMIC_RELAXED, __HIP_MEMORY_SCOPE_AGENT);
            } else {
                h_last[b * Hdim + j] = hkeep;
            }
            float y = valid ? hnew : 0.f;
            unsigned short yh = f2bf(y);
            yh_buf[t][wave * 4 + jj] = yh;
            yl_buf[t][wave * 4 + jj] = f2bf(y - bf2f(yh));
        }
    }

    // coalesced block writeback of cat cols [blk*32, blk*32+32)
    __syncthreads();
    for (int idx = tid; idx < 64 * 16; idx += 512) {
        int t = idx >> 4, c = (idx & 15) * 2;
        size_t off = (size_t)(b * Tdim + t) * 1024 + blk * 32 + c;
        *(unsigned*)(cath + off) = *(const unsigned*)(&yh_buf[t][c]);
        *(unsigned*)(catl + off) = *(const unsigned*)(&yl_buf[t][c]);
    }
}

// ------------------------------ attention ----------------------------------
// one block per (b,d). Scoring loop vectorized (float4 encp loads; decp+
// battn and v_w staged once in LDS). Summation order identical to scalar.

__global__ __launch_bounds__(256) void attn_kernel(
    const float* __restrict__ encp,     // (1024,512)
    const float* __restrict__ decp,     // (1024,512)
    const float* __restrict__ enc,      // (16,64,512)
    const float* __restrict__ battn,    // (512)
    const float* __restrict__ vw,       // (512)
    const float* __restrict__ vb,       // (1)
    const int* __restrict__ enc_len,    // (16)
    const int* __restrict__ dec_len,    // (16)
    unsigned short* __restrict__ cath,
    unsigned short* __restrict__ catl)
{
    const int blk = blockIdx.x;
    const int b = blk >> 6, d = blk & 63;
    const int tid = threadIdx.x;
    const size_t obase = (size_t)(b * Tdim + d) * 1024 + 512;

    if (d >= dec_len[b]) {
        for (int h = tid; h < Hdim; h += 256) { cath[obase + h] = 0; catl[obase + h] = 0; }
        return;
    }
    const int Tv = enc_len[b];

    __shared__ float dpb[512];          // decp row + battn
    __shared__ float vwl[512];          // v_w
    __shared__ float part[64][4];
    __shared__ float a_lds[64];

    if (tid < 128) {
        const float4* dp4 = (const float4*)(decp + (size_t)(b * Tdim + d) * Hdim);
        float4 dv = dp4[tid];
        float4 bb = ((const float4*)battn)[tid];
        float4 r; r.x = dv.x + bb.x; r.y = dv.y + bb.y;
        r.z = dv.z + bb.z; r.w = dv.w + bb.w;
        ((float4*)dpb)[tid] = r;
        ((float4*)vwl)[tid] = ((const float4*)vw)[tid];
    }
    __syncthreads();

    const int e = tid >> 2, p = tid & 3;
    float s = 0.f;
    if (e < Tv) {
        const float4* ep4 = (const float4*)(encp + (size_t)(b * Tdim + e) * Hdim);
        const int q0 = p * 32;          // float4 index base (g0 = p*128)
        for (int q = q0; q < q0 + 32; ++q) {
            float4 ev = ep4[q];
            s += vwl[q * 4 + 0] * fast_tanh(ev.x + dpb[q * 4 + 0]);
            s += vwl[q * 4 + 1] * fast_tanh(ev.y + dpb[q * 4 + 1]);
            s += vwl[q * 4 + 2] * fast_tanh(ev.z + dpb[q * 4 + 2]);
            s += vwl[q * 4 + 3] * fast_tanh(ev.w + dpb[q * 4 + 3]);
        }
    }
    part[e][p] = s;
    __syncthreads();

    if (tid < 64) {
        const int e2 = tid;
        float en = (e2 < Tv) ? (part[e2][0] + part[e2][1] + part[e2][2] + part[e2][3] + vb[0]) : -1e30f;
        float m = en;
#pragma unroll
        for (int off = 32; off; off >>= 1) m = fmaxf(m, __shfl_xor(m, off));
        float ex = (e2 < Tv) ? __expf(en - m) : 0.f;
        float sum = ex;
#pragma unroll
        for (int off = 32; off; off >>= 1) sum += __shfl_xor(sum, off);
        a_lds[e2] = ex / sum;
    }
    __syncthreads();

    const int h = tid * 2;
    float c0 = 0.f, c1 = 0.f;
    for (int e3 = 0; e3 < Tv; ++e3) {
        float a = a_lds[e3];
        float2 ev = *(const float2*)(enc + (size_t)(b * Tdim + e3) * Hdim + h);
        c0 += a * ev.x; c1 += a * ev.y;
    }
    unsigned short h0 = f2bf(c0), h1 = f2bf(c1);
    cath[obase + h]     = h0;  catl[obase + h]     = f2bf(c0 - bf2f(h0));
    cath[obase + h + 1] = h1;  catl[obase + h + 1] = f2bf(c1 - bf2f(h1));
}

// --------------------------- logits bf16 MFMA GEMM -------------------------
// C(1024 x 32000) = A(1024x512 bf16) @ B(32000x512 bf16)^T + bias, fp32 out
// 256x128 tile, 512 threads (8 waves: 4m x 2n of 64x64 each). R13-measured.

__global__ __launch_bounds__(512) void gemm_logits(
    const unsigned short* __restrict__ A,
    const unsigned short* __restrict__ B,
    const float* __restrict__ bias,
    float* __restrict__ C)
{
    const int K = Hdim;
    __shared__ unsigned short As[256 * 40];
    __shared__ unsigned short Bs[128 * 40];
    const int tid = threadIdx.x;
    const int m0 = blockIdx.y * 256, n0 = blockIdx.x * 128;
    const int wave = tid >> 6, lane = tid & 63;
    const int wm = (wave >> 1) * 64, wn = (wave & 1) * 64;
    const int lrow = lane & 15, lk = (lane >> 4) * 8;

    f32x4 acc[4][4];
#pragma unroll
    for (int i = 0; i < 4; ++i)
#pragma unroll
        for (int j = 0; j < 4; ++j) acc[i][j] = (f32x4){0.f, 0.f, 0.f, 0.f};

    for (int k0 = 0; k0 < K; k0 += 32) {
#pragma unroll
        for (int i = 0; i < 2; ++i) {
            int idx = tid + i * 512;        // 0..1023
            int rr = idx >> 2, kq = (idx & 3) * 8;
            *(uint4*)(&As[rr * 40 + kq]) = *(const uint4*)(A + (size_t)(m0 + rr) * K + k0 + kq);
        }
        {
            int rr = tid >> 2, kq = (tid & 3) * 8;
            *(uint4*)(&Bs[rr * 40 + kq]) = *(const uint4*)(B + (size_t)(n0 + rr) * K + k0 + kq);
        }
        __syncthreads();
        bf16x8 af[4], bf[4];
#pragma unroll
        for (int i = 0; i < 4; ++i) af[i] = *(const bf16x8*)(&As[(wm + i * 16 + lrow) * 40 + lk]);
#pragma unroll
        for (int j = 0; j < 4; ++j) bf[j] = *(const bf16x8*)(&Bs[(wn + j * 16 + lrow) * 40 + lk]);
#pragma unroll
        for (int i = 0; i < 4; ++i)
#pragma unroll
            for (int j = 0; j < 4; ++j)
                acc[i][j] = __builtin_amdgcn_mfma_f32_16x16x32_bf16(af[i], bf[j], acc[i][j], 0, 0, 0);
        __syncthreads();
    }

    const int crow = m0 + wm + ((lane >> 4) * 4);
    const int ccol = n0 + wn + (lane & 15);
#pragma unroll
    for (int i = 0; i < 4; ++i) {
#pragma unroll
        for (int j = 0; j < 4; ++j) {
            int col = ccol + j * 16;
            float bv = bias[col];
#pragma unroll
            for (int rr = 0; rr < 4; ++rr) {
                int row = crow + i * 16 + rr;
                C[(size_t)row * Vdim + col] = acc[i][j][rr] + bv;
            }
        }
    }
}

// ------------------------------- launcher ----------------------------------

extern "C" void kernel_launch(void* const* d_in, const int* in_sizes, int n_in,
                              void* d_out, int out_size, void* d_ws, size_t ws_size,
                              hipStream_t stream) {
    (void)in_sizes; (void)n_in; (void)out_size; (void)ws_size;

    const float* input_seqs  = (const float*)d_in[0];
    const int*   input_len   = (const int*)  d_in[1];
    const float* enc_out     = (const float*)d_in[2];
    const int*   enc_len     = (const int*)  d_in[3];
    const float* W_ih        = (const float*)d_in[4];
    const float* W_hh        = (const float*)d_in[5];
    const float* b_ih        = (const float*)d_in[6];
    const float* b_hh        = (const float*)d_in[7];
    const float* W_attn      = (const float*)d_in[8];
    const float* b_attn      = (const float*)d_in[9];
    const float* v_w         = (const float*)d_in[10];
    const float* v_b         = (const float*)d_in[11];
    const float* W_dense     = (const float*)d_in[12];
    const float* b_dense     = (const float*)d_in[13];
    const float* W_out       = (const float*)d_in[14];
    const float* b_out       = (const float*)d_in[15];

    float* logits = (float*)d_out;                        // (1024, 32000)
    float* h_last = (float*)d_out + (size_t)BT * Vdim;    // (16, 512)

    // ---- workspace layout ----
    float* ws    = (float*)d_ws;
    float* xp    = ws;                         // 1572864 f
    float* encp  = xp   + 1572864;             // 524288 f
    float* decp  = encp + 524288;              // 524288 f
    unsigned long long* hslots = (unsigned long long*)(decp + 524288); // 16384 u64
    float* zbias = (float*)(hslots + 16384);   // 512 f
    unsigned short* U0 = (unsigned short*)(zbias + 512);
    unsigned short* inp_h   = U0;               // 524288
    unsigned short* inp_l   = U0 + 524288;      // 524288
    unsigned short* Wih_h   = U0 + 1048576;     // 786432
    unsigned short* Wih_l   = U0 + 1835008;     // 786432
    unsigned short* Wattn_h = U0 + 2621440;     // 524288
    unsigned short* Wattn_l = U0 + 3145728;     // 524288
    unsigned short* Wden_h  = U0 + 3670016;     // 524288
    unsigned short* Wden_l  = U0 + 4194304;     // 524288
    unsigned short* enc_h   = U0 + 4718592;     // 524288
    unsigned short* enc_l   = U0 + 5242880;     // 524288
    unsigned short* Wout_bf = U0 + 5767168;     // 16384000
    // cat hi/lo alias the inp/Wih splits (dead after x_proj):
    unsigned short* cath = U0;                  // 1048576 (1024x1024)
    unsigned short* catl = U0 + 1048576;        // 1048576
    // dense_bf aliases encp (dead after attn):
    unsigned short* dense_bf = (unsigned short*)encp;   // 524288

    // 1. preprocessing (zero + splits; no W_out)
    preproc_kernel<<<1024, 256, 0, stream>>>(
        input_seqs, W_ih, W_attn, W_dense, enc_out,
        (float*)hslots,
        inp_h, inp_l, Wih_h, Wih_l, Wattn_h, Wattn_l,
        Wden_h, Wden_l, enc_h, enc_l);

    // 2. x_proj (1024x1536,K=512) + enc_p (1024x512,K=512) in ONE launch
    gemm_split_dual<<<128, 256, 0, stream>>>(
        inp_h, inp_l, Wih_h, Wih_l, b_ih, xp,
        enc_h, enc_l, Wattn_h, Wattn_l, zbias, encp);

    // 3. GRU (R6 protocol + R13 compute, both frozen)
    gru_persistent<<<Bdim * GANG_BLOCKS, 512, 0, stream>>>(
        xp, W_hh, b_hh, input_len, hslots, cath, catl, h_last);

    // 4. dec_p (32 blocks) + W_out f32->bf16 cvt (224 filler blocks)
    gemm_decp_cvt<<<256, 256, 0, stream>>>(
        cath, catl, Wattn_h + 512, Wattn_l + 512, zbias, decp,
        W_out, Wout_bf);

    // 5. attention -> cat cols [512,1024) hi/lo bf16 (vectorized scoring)
    attn_kernel<<<BT, 256, 0, stream>>>(encp, decp, enc_out, b_attn, v_w, v_b,
                                        enc_len, input_len, cath, catl);

    // 6. dense = tanh(cat @ W_dense^T + b_dense) -> bf16 directly (K=1024)
    gemm_split<<<dim3(Hdim / 128, BT / 128), 256, 0, stream>>>(
        cath, catl, 1024, Wden_h, Wden_l, 1024, b_dense, nullptr, dense_bf, Hdim, 1024, 1);

    // 7. logits = dense @ W_out^T + b_out  (1024 x 32000, K=512, 256x128)
    gemm_logits<<<dim3(Vdim / 128, BT / 256), 512, 0, stream>>>(
        dense_bf, Wout_bf, b_out, logits);
}

// Round 13
// 647.063 us; speedup vs baseline: 2.1546x; 1.0194x over previous
//
#include <hip/hip_runtime.h>
#include <stdint.h>

// ---------------------------------------------------------------------------
// Decoder: GRU(seq) + attention + dense + vocab projection
// H=512, V=32000, B=16, Td=Te=64
// Round 17 (base = R13 best 655.6 = GRU 279 + non-GRU 376):
//  - Small-GEMM latency fix: dual/dec_p/dense go 256-thr/4-wave ->
//    512-thr/8-wave on the SAME 128x128 tile (wave grid 2m x 4n, 64x32
//    per wave, acc[4][2]). dec_p/dense run 32 blocks on 256 CUs at
//    1 wave/SIMD = zero latency hiding; 8 waves give 2/SIMD, halve the
//    per-wave MFMA chain per K-iter, 1-iter staging. Bit-identical MFMA
//    accumulation order -> identical numerics.
//  - Everything else FROZEN at measured best: GRU (R6 protocol + R13
//    compute, 279us floor, 8x repro), logits 256x128/512thr (R13; 256x256
//    was -13us in R15 A/B), W_out cvt in big preproc (R13; GRU-fusion
//    -73us R11, dec_p-filler -4us R16), attn vectorized, pair-operand
//    staging (split-on-the-fly was -60us, R12).
//  - split-bf16 MFMA everywhere (AhBh+AhBl+AlBh, ~1.6e-5 rel err).
// ---------------------------------------------------------------------------

#define Hdim 512
#define Vdim 32000
#define Bdim 16
#define Tdim 64
#define BT   1024   // B*Td rows
#define GANG_BLOCKS 16

typedef __attribute__((ext_vector_type(8))) short bf16x8;
typedef __attribute__((ext_vector_type(4))) float f32x4;

static __device__ __forceinline__ unsigned short f2bf(float f) {
    unsigned u = __float_as_uint(f);
    u = u + 0x7FFFu + ((u >> 16) & 1u);   // RNE
    return (unsigned short)(u >> 16);
}
static __device__ __forceinline__ float bf2f(unsigned short h) {
    return __uint_as_float((unsigned)h << 16);
}
static __device__ __forceinline__ float fast_tanh(float x) {
    return 2.f / (1.f + __expf(-2.f * x)) - 1.f;
}

// --------------------------- merged preprocessing --------------------------
// Zero hslots+zbias, five f32->(hi,lo) splits, W_out f32->bf16.

#define U_ZERO 8320      // (16384 u64 -> 32768 f) + 512 f zbias, /4
#define U_INP  131072    // 1024*512/4
#define U_WIH  196608    // 1536*512/4
#define U_WAT  131072    // 512*1024/4
#define U_WDE  131072    // 512*1024/4
#define U_ENC  131072    // 1024*512/4
#define U_SPLIT (U_INP + U_WIH + U_WAT + U_WDE + U_ENC)
#define U_WOUT 4096000   // 32000*512/4
#define U_TOT  (U_ZERO + U_SPLIT + U_WOUT)

__global__ __launch_bounds__(256) void preproc_kernel(
    const float* __restrict__ input_seqs,
    const float* __restrict__ W_ih,
    const float* __restrict__ W_attn,
    const float* __restrict__ W_dense,
    const float* __restrict__ enc,
    const float* __restrict__ W_out,
    float* __restrict__ zero_base,      // hslots..zbias, 33280 floats
    unsigned short* __restrict__ inp_h, unsigned short* __restrict__ inp_l,
    unsigned short* __restrict__ Wih_h, unsigned short* __restrict__ Wih_l,
    unsigned short* __restrict__ Wat_h, unsigned short* __restrict__ Wat_l,
    unsigned short* __restrict__ Wde_h, unsigned short* __restrict__ Wde_l,
    unsigned short* __restrict__ enc_h, unsigned short* __restrict__ enc_l,
    unsigned short* __restrict__ Wout_bf)
{
    int u = blockIdx.x * 256 + threadIdx.x;
    const int stride = gridDim.x * 256;
    for (; u < U_TOT; u += stride) {
        int r = u;
        if (r < U_ZERO) {
            float4 z; z.x = 0.f; z.y = 0.f; z.z = 0.f; z.w = 0.f;
            *(float4*)(zero_base + r * 4) = z;
            continue;
        }
        r -= U_ZERO;
        if (r >= U_SPLIT) {
            int i = (r - U_SPLIT) * 4;
            float4 v = *(const float4*)(W_out + i);
            unsigned short h[4] = {f2bf(v.x), f2bf(v.y), f2bf(v.z), f2bf(v.w)};
            *(uint2*)(Wout_bf + i) = *(const uint2*)h;
            continue;
        }
        const float* src; unsigned short* hi; unsigned short* lo;
        if (r < U_INP) { src = input_seqs; hi = inp_h; lo = inp_l; }
        else { r -= U_INP;
            if (r < U_WIH) { src = W_ih; hi = Wih_h; lo = Wih_l; }
            else { r -= U_WIH;
                if (r < U_WAT) { src = W_attn; hi = Wat_h; lo = Wat_l; }
                else { r -= U_WAT;
                    if (r < U_WDE) { src = W_dense; hi = Wde_h; lo = Wde_l; }
                    else { r -= U_WDE; src = enc; hi = enc_h; lo = enc_l; }
                }
            }
        }
        int i = r * 4;
        float4 v = *(const float4*)(src + i);
        float f[4] = {v.x, v.y, v.z, v.w};
        unsigned short h[4], l[4];
#pragma unroll
        for (int k = 0; k < 4; ++k) {
            h[k] = f2bf(f[k]);
            l[k] = f2bf(f[k] - bf2f(h[k]));
        }
        *(uint2*)(hi + i) = *(const uint2*)h;
        *(uint2*)(lo + i) = *(const uint2*)l;
    }
}

// ----------------------- split-bf16 MFMA GEMM body -------------------------
// 512-thread variant: 128x128 tile, 8 waves as 2m x 4n (64x32 per wave).
// Identical MFMA accumulation order per output element as the 256-thr
// version -> bit-identical results.

struct GemmSmem {
    unsigned short AsH[128 * 40];
    unsigned short AsL[128 * 40];
    unsigned short BsH[128 * 40];
    unsigned short BsL[128 * 40];
};

static __device__ __forceinline__ void gemm_tile512(
    GemmSmem& S, int m0, int n0,
    const unsigned short* __restrict__ Ah, const unsigned short* __restrict__ Al, int lda,
    const unsigned short* __restrict__ Bh, const unsigned short* __restrict__ Bl, int ldb,
    const float* __restrict__ bias,
    float* __restrict__ C, unsigned short* __restrict__ Cb, int ldc,
    int K, int act)
{
    const int tid = threadIdx.x;
    const int wave = tid >> 6, lane = tid & 63;
    const int wm = (wave >> 2) * 64, wn = (wave & 3) * 32;
    const int lrow = lane & 15, lk = (lane >> 4) * 8;

    f32x4 acc[4][2];
#pragma unroll
    for (int i = 0; i < 4; ++i)
#pragma unroll
        for (int j = 0; j < 2; ++j) acc[i][j] = (f32x4){0.f, 0.f, 0.f, 0.f};

    for (int k0 = 0; k0 < K; k0 += 32) {
        {
            int rr = tid >> 2, kq = (tid & 3) * 8;    // 512 thr = 1 iter
            size_t ao = (size_t)(m0 + rr) * lda + k0 + kq;
            size_t bo = (size_t)(n0 + rr) * ldb + k0 + kq;
            *(uint4*)(&S.AsH[rr * 40 + kq]) = *(const uint4*)(Ah + ao);
            *(uint4*)(&S.AsL[rr * 40 + kq]) = *(const uint4*)(Al + ao);
            *(uint4*)(&S.BsH[rr * 40 + kq]) = *(const uint4*)(Bh + bo);
            *(uint4*)(&S.BsL[rr * 40 + kq]) = *(const uint4*)(Bl + bo);
        }
        __syncthreads();
        bf16x8 ah[4], al[4], bh[2], bl[2];
#pragma unroll
        for (int i = 0; i < 4; ++i) {
            ah[i] = *(const bf16x8*)(&S.AsH[(wm + i * 16 + lrow) * 40 + lk]);
            al[i] = *(const bf16x8*)(&S.AsL[(wm + i * 16 + lrow) * 40 + lk]);
        }
#pragma unroll
        for (int j = 0; j < 2; ++j) {
            bh[j] = *(const bf16x8*)(&S.BsH[(wn + j * 16 + lrow) * 40 + lk]);
            bl[j] = *(const bf16x8*)(&S.BsL[(wn + j * 16 + lrow) * 40 + lk]);
        }
#pragma unroll
        for (int i = 0; i < 4; ++i)
#pragma unroll
            for (int j = 0; j < 2; ++j) {
                acc[i][j] = __builtin_amdgcn_mfma_f32_16x16x32_bf16(ah[i], bh[j], acc[i][j], 0, 0, 0);
                acc[i][j] = __builtin_amdgcn_mfma_f32_16x16x32_bf16(ah[i], bl[j], acc[i][j], 0, 0, 0);
                acc[i][j] = __builtin_amdgcn_mfma_f32_16x16x32_bf16(al[i], bh[j], acc[i][j], 0, 0, 0);
            }
        __syncthreads();
    }

    const int crow = m0 + wm + ((lane >> 4) * 4);
    const int ccol = n0 + wn + (lane & 15);
#pragma unroll
    for (int i = 0; i < 4; ++i) {
#pragma unroll
        for (int j = 0; j < 2; ++j) {
            int col = ccol + j * 16;
            float bv = bias[col];
#pragma unroll
            for (int rr = 0; rr < 4; ++rr) {
                int row = crow + i * 16 + rr;
                float v = acc[i][j][rr] + bv;
                if (act == 1) v = fast_tanh(v);
                if (Cb) Cb[(size_t)row * ldc + col] = f2bf(v);
                else    C [(size_t)row * ldc + col] = v;
            }
        }
    }
}

// single-job GEMM (dec_p, dense), 512 thr
__global__ __launch_bounds__(512) void gemm_split(
    const unsigned short* __restrict__ Ah, const unsigned short* __restrict__ Al, int lda,
    const unsigned short* __restrict__ Bh, const unsigned short* __restrict__ Bl, int ldb,
    const float* __restrict__ bias,
    float* __restrict__ C, unsigned short* __restrict__ Cb, int ldc,
    int K, int act)
{
    __shared__ GemmSmem S;
    gemm_tile512(S, blockIdx.y * 128, blockIdx.x * 128,
                 Ah, Al, lda, Bh, Bl, ldb, bias, C, Cb, ldc, K, act);
}

// dual-job GEMM: job A = x_proj (96 blocks), job B = enc_p (32 blocks)
__global__ __launch_bounds__(512) void gemm_split_dual(
    const unsigned short* __restrict__ A0h, const unsigned short* __restrict__ A0l,
    const unsigned short* __restrict__ B0h, const unsigned short* __restrict__ B0l,
    const float* __restrict__ bias0, float* __restrict__ C0,
    const unsigned short* __restrict__ A1h, const unsigned short* __restrict__ A1l,
    const unsigned short* __restrict__ B1h, const unsigned short* __restrict__ B1l,
    const float* __restrict__ bias1, float* __restrict__ C1)
{
    __shared__ GemmSmem S;
    const int bid = blockIdx.x;
    if (bid < 96) {
        gemm_tile512(S, (bid / 12) * 128, (bid % 12) * 128,
                     A0h, A0l, Hdim, B0h, B0l, Hdim, bias0, C0, nullptr, 1536, Hdim, 0);
    } else {
        int r = bid - 96;
        gemm_tile512(S, (r / 4) * 128, (r % 4) * 128,
                     A1h, A1l, Hdim, B1h, B1l, 1024, bias1, C1, nullptr, Hdim, Hdim, 0);
    }
}

// --------------------------- persistent GRU --------------------------------
// R6 topology + R13 compute, BOTH FROZEN (floor 4.3-4.4us/step, 8x repro).
// 16 gangs x 16 blocks x 512 thr. Block owns 32 units; wave w owns
// j0 = blk*32 + w*4 (12 W_hh rows in regs, STATIC indexing). h unit j
// parity p at hslots[p*8192 + b*512 + j] as (tag=t)<<32|bits. Wave 0 polls
// its 8 units/lane (tag==t), stages TRANSPOSED into LDS hl[par][q*64+lane]
// (conflict-free), one __syncthreads, all 8 waves compute. Publish = plain
// relaxed agent store. y buffered in LDS, coalesced writeback after loop.

__global__ __launch_bounds__(512) void gru_persistent(
    const float* __restrict__ xp,        // (1024,1536) rows = b*64+t
    const float* __restrict__ Whh,       // (1536,512)
    const float* __restrict__ bhh,       // (1536)
    const int*   __restrict__ lengths,   // (16)
    unsigned long long* __restrict__ hslots, // (2,16,512) tagged; zero-init
    unsigned short* __restrict__ cath,   // (1024,1024) cols [0,512)
    unsigned short* __restrict__ catl,
    float* __restrict__ h_last)          // (16,512)
{
    const int bid  = blockIdx.x;
    const int b    = bid >> 4;           // gang = batch
    const int blk  = bid & 15;
    const int tid  = threadIdx.x;
    const int wave = tid >> 6, lane = tid & 63;
    const int j0 = blk * 32 + wave * 4;  // this wave's 4 hidden units
    const int k0 = lane * 8;

    __shared__ float hl[2][512];                // transposed [q*64+lane]
    __shared__ unsigned short yh_buf[64][32];   // [t][unit-in-block] hi
    __shared__ unsigned short yl_buf[64][32];   // [t][unit-in-block] lo

    // --- W_hh slice into registers (once): 12 rows x 8 k-elems ---
    float w[12][8];
#pragma unroll
    for (int g = 0; g < 3; ++g)
#pragma unroll
        for (int jj = 0; jj < 4; ++jj) {
            const float* src = Whh + (size_t)(g * 512 + j0 + jj) * Hdim + k0;
            float4 a = *(const float4*)src;
            float4 bq = *(const float4*)(src + 4);
            int r = g * 4 + jj;
            w[r][0] = a.x;  w[r][1] = a.y;  w[r][2] = a.z;  w[r][3] = a.w;
            w[r][4] = bq.x; w[r][5] = bq.y; w[r][6] = bq.z; w[r][7] = bq.w;
        }

    const int j = j0 + (lane & 3);       // output unit for lanes 0..3
    float bh_r = 0.f, bh_z = 0.f, bh_n = 0.f;
    if (lane < 4) {
        bh_r = bhh[j]; bh_z = bhh[512 + j]; bh_n = bhh[1024 + j];
    }
    const int len_b = lengths[b];
    float hprev = 0.f;                   // this lane's own h[b][j] (h0 = 0)

    const size_t PSTR = (size_t)Bdim * Hdim;           // parity stride
    unsigned long long* gslot = hslots + (size_t)b * Hdim;
    const float* xbase = xp + (size_t)b * Tdim * 1536;

    for (int t = 0; t < Tdim; ++t) {
        const int par = t & 1;

        // xp loads are independent of h -> issue early
        float xr = 0.f, xz = 0.f, xn = 0.f;
        if (lane < 4) {
            const float* xrow = xbase + (size_t)t * 1536;
            xr = xrow[j]; xz = xrow[512 + j]; xn = xrow[1024 + j];
        }

        // wave 0: poll tagged slots (units lane*8 .. +7), stage transposed
        if (wave == 0) {
            const unsigned long long* sl = gslot + (size_t)par * PSTR + k0;
            unsigned long long v[8];
            bool ok;
            do {
#pragma unroll
                for (int q = 0; q < 8; ++q)
                    v[q] = __hip_atomic_load(sl + q, __ATOMIC_RELAXED,
                                             __HIP_MEMORY_SCOPE_AGENT);
                ok = true;
#pragma unroll
                for (int q = 0; q < 8; ++q)
                    ok = ok && ((unsigned)(v[q] >> 32) == (unsigned)t);
            } while (!ok);
#pragma unroll
            for (int q = 0; q < 8; ++q)   // unit lane*8+q -> [q*64+lane]
                hl[par][q * 64 + lane] = __uint_as_float((unsigned)v[q]);
        }
        __syncthreads();                  // SYNC_t: hl[par] ready

        float hv[8];
#pragma unroll
        for (int q = 0; q < 8; ++q) hv[q] = hl[par][q * 64 + lane];

        float p[12];
#pragma unroll
        for (int r = 0; r < 12; ++r) {
            float s = 0.f;
#pragma unroll
            for (int k = 0; k < 8; ++k) s += w[r][k] * hv[k];
            p[r] = s;
        }

        // butterfly reduce across 64 lanes
#pragma unroll
        for (int off = 1; off < 64; off <<= 1)
#pragma unroll
            for (int r = 0; r < 12; ++r)
                p[r] += __shfl_xor(p[r], off);

        if (lane < 4) {
            const int jj = lane;
            float hr = p[jj]     + bh_r;
            float hz = p[4 + jj] + bh_z;
            float hn = p[8 + jj] + bh_n;
            float rg = 1.f / (1.f + __expf(-(xr + hr)));
            float zg = 1.f / (1.f + __expf(-(xz + hz)));
            float ng = fast_tanh(xn + rg * hn);
            float hnew = (1.f - zg) * ng + zg * hprev;
            bool valid = t < len_b;
            float hkeep = valid ? hnew : hprev;
            hprev = hkeep;
            // publish FIRST (gang-wide critical path): plain relaxed store
            if (t < Tdim - 1) {
                unsigned long long pv =
                    ((unsigned long long)(unsigned)(t + 1) << 32) |
                    (unsigned long long)__float_as_uint(hkeep);
                __hip_atomic_store(gslot + (size_t)((t + 1) & 1) * PSTR + j, pv,
                                   __ATOMIC_RELAXED, __HIP_MEMORY_SCOPE_AGENT);
            } else {
                h_last[b * Hdim + j] = hkeep;
            }
            float y = valid ? hnew : 0.f;
            unsigned short yh = f2bf(y);
            yh_buf[t][wave * 4 + jj] = yh;
            yl_buf[t][wave * 4 + jj] = f2bf(y - bf2f(yh));
        }
    }

    // coalesced block writeback of cat cols [blk*32, blk*32+32)
    __syncthreads();
    for (int idx = tid; idx < 64 * 16; idx += 512) {
        int t = idx >> 4, c = (idx & 15) * 2;
        size_t off = (size_t)(b * Tdim + t) * 1024 + blk * 32 + c;
        *(unsigned*)(cath + off) = *(const unsigned*)(&yh_buf[t][c]);
        *(unsigned*)(catl + off) = *(const unsigned*)(&yl_buf[t][c]);
    }
}

// ------------------------------ attention ----------------------------------
// one block per (b,d). Scoring loop vectorized (float4 encp loads; decp+
// battn and v_w staged once in LDS). Summation order identical to scalar.

__global__ __launch_bounds__(256) void attn_kernel(
    const float* __restrict__ encp,     // (1024,512)
    const float* __restrict__ decp,     // (1024,512)
    const float* __restrict__ enc,      // (16,64,512)
    const float* __restrict__ battn,    // (512)
    const float* __restrict__ vw,       // (512)
    const float* __restrict__ vb,       // (1)
    const int* __restrict__ enc_len,    // (16)
    const int* __restrict__ dec_len,    // (16)
    unsigned short* __restrict__ cath,
    unsigned short* __restrict__ catl)
{
    const int blk = blockIdx.x;
    const int b = blk >> 6, d = blk & 63;
    const int tid = threadIdx.x;
    const size_t obase = (size_t)(b * Tdim + d) * 1024 + 512;

    if (d >= dec_len[b]) {
        for (int h = tid; h < Hdim; h += 256) { cath[obase + h] = 0; catl[obase + h] = 0; }
        return;
    }
    const int Tv = enc_len[b];

    __shared__ float dpb[512];          // decp row + battn
    __shared__ float vwl[512];          // v_w
    __shared__ float part[64][4];
    __shared__ float a_lds[64];

    if (tid < 128) {
        const float4* dp4 = (const float4*)(decp + (size_t)(b * Tdim + d) * Hdim);
        float4 dv = dp4[tid];
        float4 bb = ((const float4*)battn)[tid];
        float4 r; r.x = dv.x + bb.x; r.y = dv.y + bb.y;
        r.z = dv.z + bb.z; r.w = dv.w + bb.w;
        ((float4*)dpb)[tid] = r;
        ((float4*)vwl)[tid] = ((const float4*)vw)[tid];
    }
    __syncthreads();

    const int e = tid >> 2, p = tid & 3;
    float s = 0.f;
    if (e < Tv) {
        const float4* ep4 = (const float4*)(encp + (size_t)(b * Tdim + e) * Hdim);
        const int q0 = p * 32;          // float4 index base (g0 = p*128)
        for (int q = q0; q < q0 + 32; ++q) {
            float4 ev = ep4[q];
            s += vwl[q * 4 + 0] * fast_tanh(ev.x + dpb[q * 4 + 0]);
            s += vwl[q * 4 + 1] * fast_tanh(ev.y + dpb[q * 4 + 1]);
            s += vwl[q * 4 + 2] * fast_tanh(ev.z + dpb[q * 4 + 2]);
            s += vwl[q * 4 + 3] * fast_tanh(ev.w + dpb[q * 4 + 3]);
        }
    }
    part[e][p] = s;
    __syncthreads();

    if (tid < 64) {
        const int e2 = tid;
        float en = (e2 < Tv) ? (part[e2][0] + part[e2][1] + part[e2][2] + part[e2][3] + vb[0]) : -1e30f;
        float m = en;
#pragma unroll
        for (int off = 32; off; off >>= 1) m = fmaxf(m, __shfl_xor(m, off));
        float ex = (e2 < Tv) ? __expf(en - m) : 0.f;
        float sum = ex;
#pragma unroll
        for (int off = 32; off; off >>= 1) sum += __shfl_xor(sum, off);
        a_lds[e2] = ex / sum;
    }
    __syncthreads();

    const int h = tid * 2;
    float c0 = 0.f, c1 = 0.f;
    for (int e3 = 0; e3 < Tv; ++e3) {
        float a = a_lds[e3];
        float2 ev = *(const float2*)(enc + (size_t)(b * Tdim + e3) * Hdim + h);
        c0 += a * ev.x; c1 += a * ev.y;
    }
    unsigned short h0 = f2bf(c0), h1 = f2bf(c1);
    cath[obase + h]     = h0;  catl[obase + h]     = f2bf(c0 - bf2f(h0));
    cath[obase + h + 1] = h1;  catl[obase + h + 1] = f2bf(c1 - bf2f(h1));
}

// --------------------------- logits bf16 MFMA GEMM -------------------------
// C(1024 x 32000) = A(1024x512 bf16) @ B(32000x512 bf16)^T + bias, fp32 out
// 256x128 tile, 512 threads (8 waves: 4m x 2n of 64x64 each). R13-measured.

__global__ __launch_bounds__(512) void gemm_logits(
    const unsigned short* __restrict__ A,
    const unsigned short* __restrict__ B,
    const float* __restrict__ bias,
    float* __restrict__ C)
{
    const int K = Hdim;
    __shared__ unsigned short As[256 * 40];
    __shared__ unsigned short Bs[128 * 40];
    const int tid = threadIdx.x;
    const int m0 = blockIdx.y * 256, n0 = blockIdx.x * 128;
    const int wave = tid >> 6, lane = tid & 63;
    const int wm = (wave >> 1) * 64, wn = (wave & 1) * 64;
    const int lrow = lane & 15, lk = (lane >> 4) * 8;

    f32x4 acc[4][4];
#pragma unroll
    for (int i = 0; i < 4; ++i)
#pragma unroll
        for (int j = 0; j < 4; ++j) acc[i][j] = (f32x4){0.f, 0.f, 0.f, 0.f};

    for (int k0 = 0; k0 < K; k0 += 32) {
#pragma unroll
        for (int i = 0; i < 2; ++i) {
            int idx = tid + i * 512;        // 0..1023
            int rr = idx >> 2, kq = (idx & 3) * 8;
            *(uint4*)(&As[rr * 40 + kq]) = *(const uint4*)(A + (size_t)(m0 + rr) * K + k0 + kq);
        }
        {
            int rr = tid >> 2, kq = (tid & 3) * 8;
            *(uint4*)(&Bs[rr * 40 + kq]) = *(const uint4*)(B + (size_t)(n0 + rr) * K + k0 + kq);
        }
        __syncthreads();
        bf16x8 af[4], bf[4];
#pragma unroll
        for (int i = 0; i < 4; ++i) af[i] = *(const bf16x8*)(&As[(wm + i * 16 + lrow) * 40 + lk]);
#pragma unroll
        for (int j = 0; j < 4; ++j) bf[j] = *(const bf16x8*)(&Bs[(wn + j * 16 + lrow) * 40 + lk]);
#pragma unroll
        for (int i = 0; i < 4; ++i)
#pragma unroll
            for (int j = 0; j < 4; ++j)
                acc[i][j] = __builtin_amdgcn_mfma_f32_16x16x32_bf16(af[i], bf[j], acc[i][j], 0, 0, 0);
        __syncthreads();
    }

    const int crow = m0 + wm + ((lane >> 4) * 4);
    const int ccol = n0 + wn + (lane & 15);
#pragma unroll
    for (int i = 0; i < 4; ++i) {
#pragma unroll
        for (int j = 0; j < 4; ++j) {
            int col = ccol + j * 16;
            float bv = bias[col];
#pragma unroll
            for (int rr = 0; rr < 4; ++rr) {
                int row = crow + i * 16 + rr;
                C[(size_t)row * Vdim + col] = acc[i][j][rr] + bv;
            }
        }
    }
}

// ------------------------------- launcher ----------------------------------

extern "C" void kernel_launch(void* const* d_in, const int* in_sizes, int n_in,
                              void* d_out, int out_size, void* d_ws, size_t ws_size,
                              hipStream_t stream) {
    (void)in_sizes; (void)n_in; (void)out_size; (void)ws_size;

    const float* input_seqs  = (const float*)d_in[0];
    const int*   input_len   = (const int*)  d_in[1];
    const float* enc_out     = (const float*)d_in[2];
    const int*   enc_len     = (const int*)  d_in[3];
    const float* W_ih        = (const float*)d_in[4];
    const float* W_hh        = (const float*)d_in[5];
    const float* b_ih        = (const float*)d_in[6];
    const float* b_hh        = (const float*)d_in[7];
    const float* W_attn      = (const float*)d_in[8];
    const float* b_attn      = (const float*)d_in[9];
    const float* v_w         = (const float*)d_in[10];
    const float* v_b         = (const float*)d_in[11];
    const float* W_dense     = (const float*)d_in[12];
    const float* b_dense     = (const float*)d_in[13];
    const float* W_out       = (const float*)d_in[14];
    const float* b_out       = (const float*)d_in[15];

    float* logits = (float*)d_out;                        // (1024, 32000)
    float* h_last = (float*)d_out + (size_t)BT * Vdim;    // (16, 512)

    // ---- workspace layout ----
    float* ws    = (float*)d_ws;
    float* xp    = ws;                         // 1572864 f
    float* encp  = xp   + 1572864;             // 524288 f
    float* decp  = encp + 524288;              // 524288 f
    unsigned long long* hslots = (unsigned long long*)(decp + 524288); // 16384 u64
    float* zbias = (float*)(hslots + 16384);   // 512 f
    unsigned short* U0 = (unsigned short*)(zbias + 512);
    unsigned short* inp_h   = U0;               // 524288
    unsigned short* inp_l   = U0 + 524288;      // 524288
    unsigned short* Wih_h   = U0 + 1048576;     // 786432
    unsigned short* Wih_l   = U0 + 1835008;     // 786432
    unsigned short* Wattn_h = U0 + 2621440;     // 524288
    unsigned short* Wattn_l = U0 + 3145728;     // 524288
    unsigned short* Wden_h  = U0 + 3670016;     // 524288
    unsigned short* Wden_l  = U0 + 4194304;     // 524288
    unsigned short* enc_h   = U0 + 4718592;     // 524288
    unsigned short* enc_l   = U0 + 5242880;     // 524288
    unsigned short* Wout_bf = U0 + 5767168;     // 16384000
    // cat hi/lo alias the inp/Wih splits (dead after x_proj):
    unsigned short* cath = U0;                  // 1048576 (1024x1024)
    unsigned short* catl = U0 + 1048576;        // 1048576
    // dense_bf aliases encp (dead after attn):
    unsigned short* dense_bf = (unsigned short*)encp;   // 524288

    // 1. merged preprocessing (zero + splits + W_out cvt, full-grid)
    preproc_kernel<<<4096, 256, 0, stream>>>(
        input_seqs, W_ih, W_attn, W_dense, enc_out, W_out,
        (float*)hslots,
        inp_h, inp_l, Wih_h, Wih_l, Wattn_h, Wattn_l,
        Wden_h, Wden_l, enc_h, enc_l, Wout_bf);

    // 2. x_proj (1024x1536,K=512) + enc_p (1024x512,K=512) in ONE launch
    gemm_split_dual<<<128, 512, 0, stream>>>(
        inp_h, inp_l, Wih_h, Wih_l, b_ih, xp,
        enc_h, enc_l, Wattn_h, Wattn_l, zbias, encp);

    // 3. GRU (R6 protocol + R13 compute, both frozen)
    gru_persistent<<<Bdim * GANG_BLOCKS, 512, 0, stream>>>(
        xp, W_hh, b_hh, input_len, hslots, cath, catl, h_last);

    // 4. dec_p = dec_out @ Wd^T (A = cat pair, lda=1024), no bias
    gemm_split<<<dim3(Hdim / 128, BT / 128), 512, 0, stream>>>(
        cath, catl, 1024, Wattn_h + 512, Wattn_l + 512, 1024, zbias, decp, nullptr, Hdim, Hdim, 0);

    // 5. attention -> cat cols [512,1024) hi/lo bf16 (vectorized scoring)
    attn_kernel<<<BT, 256, 0, stream>>>(encp, decp, enc_out, b_attn, v_w, v_b,
                                        enc_len, input_len, cath, catl);

    // 6. dense = tanh(cat @ W_dense^T + b_dense) -> bf16 directly (K=1024)
    gemm_split<<<dim3(Hdim / 128, BT / 128), 512, 0, stream>>>(
        cath, catl, 1024, Wden_h, Wden_l, 1024, b_dense, nullptr, dense_bf, Hdim, 1024, 1);

    // 7. logits = dense @ W_out^T + b_out  (1024 x 32000, K=512, 256x128)
    gemm_logits<<<dim3(Vdim / 128, BT / 256), 512, 0, stream>>>(
        dense_bf, Wout_bf, b_out, logits);
}